// Round 3
// baseline (616.564 us; speedup 1.0000x reference)
//
#include <hip/hip_runtime.h>
#include <math.h>

// ---- problem constants (from reference) ----
constexpr int Bq = 4, Tq = 2048, Dq = 512, Hq = 4, DKq = 64, DVq = 128, LRq = 32;
constexpr int Mq = Bq * Tq;           // 8192 rows
constexpr int CL = 64;                // scan chunk length
constexpr int NCq = Tq / CL;          // 32 chunks
constexpr float EPSq = 1e-5f;

typedef unsigned short u16;
typedef __attribute__((ext_vector_type(8))) short short8v;  // 8 bf16 (4 VGPR)
typedef __attribute__((ext_vector_type(4))) float f32x4;

// float -> bf16 (round-to-nearest-even)
__device__ __forceinline__ u16 f2b(float f) {
    unsigned u = __float_as_uint(f);
    u += 0x7fffu + ((u >> 16) & 1);
    return (u16)(u >> 16);
}

// async global->LDS, 16B per lane (dest = uniform base + lane*16)
__device__ __forceinline__ void gl_lds16(const void* g, void* l) {
    __builtin_amdgcn_global_load_lds(
        (const __attribute__((address_space(1))) unsigned int*)g,
        (__attribute__((address_space(3))) unsigned int*)l, 16, 0, 0);
}

// ============================================================
// LayerNorm kernels (fp32)
// ============================================================
__global__ __launch_bounds__(256)
void k_ln01(const float* __restrict__ x,
            const float* __restrict__ g0, const float* __restrict__ b0,
            const float* __restrict__ g1, const float* __restrict__ b1,
            float* __restrict__ Rout, float* __restrict__ Hout) {
    __shared__ float red[8];
    int row = blockIdx.x, tid = threadIdx.x;
    const float* xr = x + (size_t)row * Dq;
    float v0 = xr[tid], v1 = xr[tid + 256];

    float s = v0 + v1, q = v0 * v0 + v1 * v1;
#pragma unroll
    for (int o = 32; o; o >>= 1) { s += __shfl_down(s, o); q += __shfl_down(q, o); }
    if ((tid & 63) == 0) { red[tid >> 6] = s; red[4 + (tid >> 6)] = q; }
    __syncthreads();
    s = red[0] + red[1] + red[2] + red[3];
    q = red[4] + red[5] + red[6] + red[7];
    float mean = s * (1.f / Dq);
    float inv = rsqrtf(q * (1.f / Dq) - mean * mean + EPSq);
    float r0 = (v0 - mean) * inv * g0[tid] + b0[tid];
    float r1 = (v1 - mean) * inv * g0[tid + 256] + b0[tid + 256];
    Rout[(size_t)row * Dq + tid] = r0;
    Rout[(size_t)row * Dq + tid + 256] = r1;

    s = r0 + r1; q = r0 * r0 + r1 * r1;
#pragma unroll
    for (int o = 32; o; o >>= 1) { s += __shfl_down(s, o); q += __shfl_down(q, o); }
    __syncthreads();
    if ((tid & 63) == 0) { red[tid >> 6] = s; red[4 + (tid >> 6)] = q; }
    __syncthreads();
    s = red[0] + red[1] + red[2] + red[3];
    q = red[4] + red[5] + red[6] + red[7];
    mean = s * (1.f / Dq);
    inv = rsqrtf(q * (1.f / Dq) - mean * mean + EPSq);
    Hout[(size_t)row * Dq + tid] = (r0 - mean) * inv * g1[tid] + b1[tid];
    Hout[(size_t)row * Dq + tid + 256] = (r1 - mean) * inv * g1[tid + 256] + b1[tid + 256];
}

__global__ __launch_bounds__(256)
void k_ln(const float* __restrict__ in, const float* __restrict__ g,
          const float* __restrict__ b, float* __restrict__ out) {
    __shared__ float red[8];
    int row = blockIdx.x, tid = threadIdx.x;
    const float* xr = in + (size_t)row * Dq;
    float v0 = xr[tid], v1 = xr[tid + 256];
    float s = v0 + v1, q = v0 * v0 + v1 * v1;
#pragma unroll
    for (int o = 32; o; o >>= 1) { s += __shfl_down(s, o); q += __shfl_down(q, o); }
    if ((tid & 63) == 0) { red[tid >> 6] = s; red[4 + (tid >> 6)] = q; }
    __syncthreads();
    s = red[0] + red[1] + red[2] + red[3];
    q = red[4] + red[5] + red[6] + red[7];
    float mean = s * (1.f / Dq);
    float inv = rsqrtf(q * (1.f / Dq) - mean * mean + EPSq);
    out[(size_t)row * Dq + tid] = (v0 - mean) * inv * g[tid] + b[tid];
    out[(size_t)row * Dq + tid + 256] = (v1 - mean) * inv * g[tid + 256] + b[tid + 256];
}

// token-shift mix with constant mu vector: out = h + (shift(h)-h)*mu  -> bf16
__global__ __launch_bounds__(256)
void k_mix1(const float* __restrict__ h, const float* __restrict__ mu,
            u16* __restrict__ out) {
    int row = blockIdx.x, t = row % Tq;
    const float* hr = h + (size_t)row * Dq;
#pragma unroll
    for (int it = 0; it < 2; it++) {
        int d = threadIdx.x + it * 256;
        float hv = hr[d];
        float pv = t ? hr[d - Dq] : 0.f;
        out[(size_t)row * Dq + d] = f2b(hv + (pv - hv) * mu[d]);
    }
}

__global__ __launch_bounds__(256)
void k_mix2(const float* __restrict__ h, const float* __restrict__ muK,
            const float* __restrict__ muR, u16* __restrict__ outK,
            u16* __restrict__ outR) {
    int row = blockIdx.x, t = row % Tq;
    const float* hr = h + (size_t)row * Dq;
#pragma unroll
    for (int it = 0; it < 2; it++) {
        int d = threadIdx.x + it * 256;
        float hv = hr[d];
        float pv = t ? hr[d - Dq] : 0.f;
        float dl = pv - hv;
        outK[(size_t)row * Dq + d] = f2b(hv + dl * muK[d]);
        outR[(size_t)row * Dq + d] = f2b(hv + dl * muR[d]);
    }
}

// weight fp32 -> bf16 conversion (padded rows zeroed)
struct WConv {
    const float* src[11];
    u16* dst[11];
    int n[11];
    int npad[11];
};
__global__ __launch_bounds__(256)
void k_wconv(WConv wc) {
    int w = blockIdx.y;
    const float* s = wc.src[w];
    u16* d = wc.dst[w];
    int n = wc.n[w], np = wc.npad[w];
    for (int i = blockIdx.x * 256 + threadIdx.x; i < np; i += gridDim.x * 256)
        d[i] = (i < n) ? f2b(s[i]) : (u16)0;
}

// ============================================================
// bf16 MFMA GEMM: C[M,N] = epi( A[M,K](bf16) @ W[N,K](bf16)^T )
// 128x128 tile, BK=64, 4 waves (2x2), 4x4 16x16x32 frags/wave.
// LDS tiles XOR-swizzled (colchunk ^= row&7) via pre-swizzled
// global source so global_load_lds stays linear-dest (m173 pattern).
// ============================================================
enum MEpi { ME_NONE, ME_TANH_F32, ME_TANH_B16, ME_DECAY, ME_RESID,
            ME_RELUSQ_B16, ME_SIGMOID, ME_GATED };

template <int EPI>
__global__ __launch_bounds__(256)
void k_mgemm(const u16* __restrict__ A, int lda,
             const u16* __restrict__ W, int ldw,
             void* __restrict__ Cout, int ldc,
             int N, int K,
             const float* __restrict__ bias,   // DECAY: w_b
             const float* __restrict__ P1,     // RESID: residual ; GATED: z
             const float* __restrict__ P2) {   // GATED: rr
    __shared__ __align__(16) char smem[32768];   // sA 16KB | sB 16KB
    char* sA = smem;
    char* sB = smem + 16384;
    const int m0 = blockIdx.x * 128, n0 = blockIdx.y * 128;
    const int tid = threadIdx.x, lane = tid & 63, wid = tid >> 6;
    const int wm = wid >> 1, wn = wid & 1;     // 2x2 wave grid, 64x64 each

    f32x4 acc[4][4] = {};

    // staging: wave wid covers rows [wid*32, wid*32+32) of both tiles.
    // lane -> row (lane>>3) within an 8-row group, col-chunk (lane&7);
    // source col-chunk pre-swizzled so that LDS slot c holds chunk c^(row&7).
    const int rl = lane >> 3;
    const int ccs = (lane & 7) ^ rl;
    const u16* ga = A + (size_t)(m0 + wid * 32 + rl) * lda + ccs * 8;
    const u16* gb = W + (size_t)(n0 + wid * 32 + rl) * ldw + ccs * 8;
    char* la = sA + (wid * 32) * 128;
    char* lb = sB + (wid * 32) * 128;

    const int nkt = K >> 6;
    for (int kt = 0; kt < nkt; ++kt) {
        const int k0 = kt << 6;
#pragma unroll
        for (int i = 0; i < 4; ++i) {
            gl_lds16(ga + (size_t)(i * 8) * lda + k0, la + i * 8 * 128);
            gl_lds16(gb + (size_t)(i * 8) * ldw + k0, lb + i * 8 * 128);
        }
        asm volatile("s_waitcnt vmcnt(0)" ::: "memory");
        __syncthreads();
#pragma unroll
        for (int ks = 0; ks < 2; ++ks) {
            short8v af[4], bfr[4];
            const int cc = ks * 4 + (lane >> 4);
#pragma unroll
            for (int i = 0; i < 4; ++i) {
                const int mr = wm * 64 + i * 16 + (lane & 15);
                af[i] = *(const short8v*)(sA + mr * 128 + ((cc ^ (mr & 7)) << 4));
                const int nr = wn * 64 + i * 16 + (lane & 15);
                bfr[i] = *(const short8v*)(sB + nr * 128 + ((cc ^ (nr & 7)) << 4));
            }
#pragma unroll
            for (int i = 0; i < 4; ++i)
#pragma unroll
                for (int j = 0; j < 4; ++j)
                    acc[i][j] = __builtin_amdgcn_mfma_f32_16x16x32_bf16(
                        af[i], bfr[j], acc[i][j], 0, 0, 0);
        }
        __syncthreads();
    }

    // epilogue: C/D mapping col=lane&15, row=(lane>>4)*4+reg  [m89-verified]
    float* Cf = (float*)Cout;
    u16* Cb = (u16*)Cout;
#pragma unroll
    for (int i = 0; i < 4; ++i) {
        const int row = m0 + wm * 64 + i * 16 + (lane >> 4) * 4;
#pragma unroll
        for (int j = 0; j < 4; ++j) {
            const int col = n0 + wn * 64 + j * 16 + (lane & 15);
            if (col < N) {
#pragma unroll
                for (int r = 0; r < 4; ++r) {
                    const float v = acc[i][j][r];
                    const size_t idx = (size_t)(row + r) * ldc + col;
                    if constexpr (EPI == ME_NONE)        Cf[idx] = v;
                    else if constexpr (EPI == ME_TANH_F32) Cf[idx] = tanhf(v);
                    else if constexpr (EPI == ME_TANH_B16) Cb[idx] = f2b(tanhf(v));
                    else if constexpr (EPI == ME_DECAY)  Cf[idx] = expf(-expf(v + bias[col]));
                    else if constexpr (EPI == ME_RESID)  Cf[idx] = v + P1[idx];
                    else if constexpr (EPI == ME_RELUSQ_B16) {
                        float t = fmaxf(v, 0.f); Cb[idx] = f2b(t * t);
                    }
                    else if constexpr (EPI == ME_SIGMOID) Cf[idx] = 1.f / (1.f + __expf(-v));
                    else                                  Cf[idx] = P1[idx] + P2[idx] * v;
                }
            }
        }
    }
}

// ============================================================
// Fused 5-group LoRA-up GEMM (K=32, fp32 vector) + shift-mix epilogue -> bf16
// ============================================================
__global__ __launch_bounds__(256)
void k_gemm_mix5(const float* __restrict__ XX, const float* __restrict__ w2,
                 const float* __restrict__ xb, const float* __restrict__ Hb,
                 u16* __restrict__ AMX) {
    constexpr int BM = 64, BK = 16, K = LRq, LDX = 5 * LRq;
    __shared__ __align__(16) float sA[BK][BM + 4];
    __shared__ __align__(16) float sB[BK][BM + 4];
    int g = blockIdx.z;
    const float* A = XX + g * LRq;
    const float* W = w2 + g * LRq;
    const float* bias = xb + g * Dq;
    u16* C = AMX + (size_t)g * Mq * Dq;
    int m0 = blockIdx.x * BM, n0 = blockIdx.y * BM;
    int tid = threadIdx.x;
    int tx = tid & 15, ty = tid >> 4;
    int lr = tid >> 2, lc = (tid & 3) * 4;
    float acc[4][4] = {};

    for (int k0 = 0; k0 < K; k0 += BK) {
        float4 av = *(const float4*)(A + (size_t)(m0 + lr) * LDX + k0 + lc);
        float4 bv = *(const float4*)(W + (size_t)(n0 + lr) * LDX + k0 + lc);
        sA[lc + 0][lr] = av.x; sA[lc + 1][lr] = av.y;
        sA[lc + 2][lr] = av.z; sA[lc + 3][lr] = av.w;
        sB[lc + 0][lr] = bv.x; sB[lc + 1][lr] = bv.y;
        sB[lc + 2][lr] = bv.z; sB[lc + 3][lr] = bv.w;
        __syncthreads();
#pragma unroll
        for (int kk = 0; kk < BK; kk++) {
            float4 a4 = *(const float4*)&sA[kk][ty * 4];
            float4 b4 = *(const float4*)&sB[kk][tx * 4];
            acc[0][0] += a4.x * b4.x; acc[0][1] += a4.x * b4.y;
            acc[0][2] += a4.x * b4.z; acc[0][3] += a4.x * b4.w;
            acc[1][0] += a4.y * b4.x; acc[1][1] += a4.y * b4.y;
            acc[1][2] += a4.y * b4.z; acc[1][3] += a4.y * b4.w;
            acc[2][0] += a4.z * b4.x; acc[2][1] += a4.z * b4.y;
            acc[2][2] += a4.z * b4.z; acc[2][3] += a4.z * b4.w;
            acc[3][0] += a4.w * b4.x; acc[3][1] += a4.w * b4.y;
            acc[3][2] += a4.w * b4.z; acc[3][3] += a4.w * b4.w;
        }
        __syncthreads();
    }

#pragma unroll
    for (int i = 0; i < 4; i++) {
        int row = m0 + ty * 4 + i;
        int t = row % Tq;
#pragma unroll
        for (int j = 0; j < 4; j++) {
            int col = n0 + tx * 4 + j;
            size_t idx = (size_t)row * Dq + col;
            float val = acc[i][j] + bias[col];
            float hv = Hb[idx];
            float pv = t ? Hb[idx - Dq] : 0.f;
            C[idx] = f2b(hv + (pv - hv) * val);
        }
    }
}

// ============================================================
// Chunked linear-attention scan (exact recompute formulation, fp32)
// ============================================================
__global__ __launch_bounds__(128)
void k_chunk_local(const float* __restrict__ Kp, const float* __restrict__ Dp,
                   const float* __restrict__ Vp,
                   float* __restrict__ MC, float* __restrict__ PC) {
    int blk = blockIdx.x;
    int c = blk % NCq, h = (blk / NCq) % Hq, b = blk / (NCq * Hq);
    __shared__ float2 kd[DKq];
    float S[DKq];
#pragma unroll
    for (int k = 0; k < DKq; k++) S[k] = 0.f;
    int tid = threadIdx.x;
    float pacc = 1.f;
    for (int s = 0; s < CL; s++) {
        int t = c * CL + s;
        size_t base = (size_t)(b * Tq + t) * Hq + h;
        if (tid < DKq) {
            float kk = Kp[base * DKq + tid];
            float dd = Dp[base * DKq + tid];
            kd[tid] = make_float2(kk, dd);
            pacc *= dd;
        }
        __syncthreads();
        float vv = Vp[base * DVq + tid];
#pragma unroll
        for (int k = 0; k < DKq; k++) {
            float2 e = kd[k];
            S[k] = fmaf(e.y, S[k], e.x * vv);
        }
        __syncthreads();
    }
    size_t cb = (size_t)(b * Hq + h) * NCq + c;
    if (tid < DKq) PC[cb * DKq + tid] = pacc;
#pragma unroll
    for (int k = 0; k < DKq; k++) MC[(cb * DKq + k) * DVq + tid] = S[k];
}

__global__ __launch_bounds__(256)
void k_combine(const float* __restrict__ MC, const float* __restrict__ PC,
               float* __restrict__ S0) {
    int idx = blockIdx.x * blockDim.x + threadIdx.x;
    int v = idx % DVq;
    int k = (idx / DVq) % DKq;
    int bh = idx / (DVq * DKq);
    float s = 0.f;
    for (int c = 0; c < NCq; c++) {
        size_t cb = (size_t)bh * NCq + c;
        S0[(cb * DKq + k) * DVq + v] = s;
        s = fmaf(PC[cb * DKq + k], s, MC[(cb * DKq + k) * DVq + v]);
    }
}

__global__ __launch_bounds__(128)
void k_chunk_out(const float* __restrict__ Rp, const float* __restrict__ Kp,
                 const float* __restrict__ Dp, const float* __restrict__ Vp,
                 const float* __restrict__ S0, const float* __restrict__ bonus,
                 float* __restrict__ O) {
    int blk = blockIdx.x;
    int c = blk % NCq, h = (blk / NCq) % Hq, b = blk / (NCq * Hq);
    __shared__ float4 rkd[DKq];
    float S[DKq];
    int tid = threadIdx.x;
    size_t cb = (size_t)(b * Hq + h) * NCq + c;
#pragma unroll
    for (int k = 0; k < DKq; k++) S[k] = S0[(cb * DKq + k) * DVq + tid];
    for (int s = 0; s < CL; s++) {
        int t = c * CL + s;
        size_t base = (size_t)(b * Tq + t) * Hq + h;
        if (tid < DKq) {
            float rr = Rp[base * DKq + tid];
            float kk = Kp[base * DKq + tid];
            float dd = Dp[base * DKq + tid];
            rkd[tid] = make_float4(rr, bonus[h * DKq + tid] * kk, kk, dd);
        }
        __syncthreads();
        float vv = Vp[base * DVq + tid];
        float acc = 0.f;
#pragma unroll
        for (int k = 0; k < DKq; k++) {
            float4 e = rkd[k];
            float t0 = fmaf(e.y, vv, S[k]);       // S + bonus*k*v
            acc = fmaf(e.x, t0, acc);             // r . (...)
            S[k] = fmaf(e.w, S[k], e.z * vv);     // S = d*S + k*v
        }
        O[base * DVq + tid] = acc;
        __syncthreads();
    }
}

// per-head groupnorm + swish gate -> bf16
__global__ __launch_bounds__(128)
void k_gatenorm(const float* __restrict__ O, const float* __restrict__ G,
                const float* __restrict__ gn_g, const float* __restrict__ gn_b,
                u16* __restrict__ OB) {
    int r = blockIdx.x;  // (b,t,h)
    size_t base = (size_t)r * DVq;
    int tid = threadIdx.x;
    float v = O[base + tid];
    float s = v, q = v * v;
#pragma unroll
    for (int o = 32; o; o >>= 1) { s += __shfl_down(s, o); q += __shfl_down(q, o); }
    __shared__ float tmp[4];
    int lane = tid & 63, wid = tid >> 6;
    if (lane == 0) { tmp[wid] = s; tmp[wid + 2] = q; }
    __syncthreads();
    s = tmp[0] + tmp[1]; q = tmp[2] + tmp[3];
    float mean = s * (1.f / DVq);
    float inv = rsqrtf(q * (1.f / DVq) - mean * mean + EPSq);
    float ln = (v - mean) * inv * gn_g[tid] + gn_b[tid];
    float g = G[base + tid];
    OB[base + tid] = f2b(ln * (g / (1.f + __expf(-g))));
}

// ============================================================
// Host-side launch
// ============================================================
extern "C" void kernel_launch(void* const* d_in, const int* in_sizes, int n_in,
                              void* d_out, int out_size, void* d_ws, size_t ws_size,
                              hipStream_t stream) {
    const float* x     = (const float*)d_in[0];
    const float* ln0_g = (const float*)d_in[1];
    const float* ln0_b = (const float*)d_in[2];
    const float* ln1_g = (const float*)d_in[3];
    const float* ln1_b = (const float*)d_in[4];
    const float* ln2_g = (const float*)d_in[5];
    const float* ln2_b = (const float*)d_in[6];
    const float* xp_mu = (const float*)d_in[7];
    const float* xp_w1 = (const float*)d_in[8];   // (160,512)
    const float* xp_w2 = (const float*)d_in[9];   // (512,160)
    const float* x_bias= (const float*)d_in[10];  // (5,512)
    const float* r_w   = (const float*)d_in[11];  // (256,512)
    const float* w_A   = (const float*)d_in[12];  // (64,512)
    const float* w_B   = (const float*)d_in[13];  // (256,64)
    const float* w_b   = (const float*)d_in[14];  // (256)
    const float* k_w   = (const float*)d_in[15];  // (256,512)
    const float* v_w   = (const float*)d_in[16];  // (512,512)
    const float* g_w   = (const float*)d_in[17];  // (512,512)
    const float* bonus = (const float*)d_in[18];  // (4,64)
    const float* gn_g  = (const float*)d_in[19];  // (128)
    const float* gn_b  = (const float*)d_in[20];
    const float* o_w   = (const float*)d_in[21];  // (512,512)
    const float* fk_mu = (const float*)d_in[22];
    const float* fk_w  = (const float*)d_in[23];  // (1024,512)
    const float* fr_mu = (const float*)d_in[24];
    const float* fr_w  = (const float*)d_in[25];  // (512,512)
    const float* fv_w  = (const float*)d_in[26];  // (512,1024)
    float* out = (float*)d_out;
    (void)in_sizes; (void)n_in; (void)out_size; (void)ws_size;

    const size_t MD = (size_t)Mq * Dq;  // 4M elems
    float* ws = (float*)d_ws;
    size_t off = 0;
    auto af32 = [&](size_t n) { float* p = ws + off; off += n; return p; };

    float* R   = af32(MD);                 // ln0 out (residual), live to o-GEMM
    float* Hb  = af32(MD);                 // ln1 out, live to mix5
    float* XX  = af32((size_t)Mq * 160);   // lora-down (fp32, vector-mix5 A)
    float* RQ  = af32((size_t)Mq * 256);
    float* DEC = af32((size_t)Mq * 256);
    float* KB  = af32((size_t)Mq * 256);
    float* VB  = af32(MD);
    float* GB  = af32(MD);
    float* PC  = af32((size_t)Bq * Hq * NCq * DKq);
    float* S0  = af32((size_t)Bq * Hq * NCq * DKq * DVq);  // 4M
    float* O   = af32(MD);
    // fp32 aliases (lifetimes disjoint, stream-ordered)
    float* MC  = Hb;   // scan pass-1 states  (Hb dead after mix5)
    float* H2  = O;    // ln2 out             (O dead after gatenorm)
    float* Z   = GB;   // a + residual        (GB dead after gatenorm)
    float* RRb = VB;   // sigmoid gate        (VB dead after scan)

    u16* us = (u16*)(ws + off);
    size_t uo = 0;
    auto au16 = [&](size_t n) { u16* p = us + uo; uo += n; return p; };
    u16* MX0b = au16(MD);          // mix(h,xp_mu) bf16
    u16* AMXb = au16(5 * MD);      // 5 mixed GEMM inputs bf16
    u16* TAb  = au16((size_t)Mq * 64);
    u16* OBb  = au16(MD);          // gatenorm out bf16
    u16* wb_xp1 = au16(256 * 512); // padded 160->256 rows
    u16* wb_r   = au16(256 * 512);
    u16* wb_wA  = au16(128 * 512); // padded 64->128 rows
    u16* wb_wB  = au16(256 * 64);
    u16* wb_k   = au16(256 * 512);
    u16* wb_v   = au16(512 * 512);
    u16* wb_g   = au16(512 * 512);
    u16* wb_o   = au16(512 * 512);
    u16* wb_fk  = au16(1024 * 512);
    u16* wb_fr  = au16(512 * 512);
    u16* wb_fv  = au16(512 * 1024);
    // u16 aliases
    u16* MXKb = AMXb;              // slice 0 (dead after r-GEMM)
    u16* MXRb = AMXb + MD;         // slice 1 (dead after wA-GEMM)
    u16* KKb  = AMXb + 2 * MD;     // slices 2+3 -> [M][1024] (dead after v-GEMM)

    // 0) weights -> bf16 (padded rows zeroed)
    WConv wc;
    const float* wsrc[11] = {xp_w1, r_w, w_A, w_B, k_w, v_w, g_w, o_w, fk_w, fr_w, fv_w};
    u16* wdst[11] = {wb_xp1, wb_r, wb_wA, wb_wB, wb_k, wb_v, wb_g, wb_o, wb_fk, wb_fr, wb_fv};
    int wn_[11]  = {160*512, 256*512, 64*512, 256*64, 256*512, 512*512, 512*512,
                    512*512, 1024*512, 512*512, 512*1024};
    int wnp[11]  = {256*512, 256*512, 128*512, 256*64, 256*512, 512*512, 512*512,
                    512*512, 1024*512, 512*512, 512*1024};
    for (int i = 0; i < 11; i++) { wc.src[i] = wsrc[i]; wc.dst[i] = wdst[i];
                                   wc.n[i] = wn_[i]; wc.npad[i] = wnp[i]; }
    k_wconv<<<dim3(64, 11), 256, 0, stream>>>(wc);

    // 1) pre-norms
    k_ln01<<<Mq, 256, 0, stream>>>(x, ln0_g, ln0_b, ln1_g, ln1_b, R, Hb);

    // 2) xx = tanh(mix(h, xp_mu) @ xp_w1^T)   [MFMA]
    k_mix1<<<Mq, 256, 0, stream>>>(Hb, xp_mu, MX0b);
    k_mgemm<ME_TANH_F32><<<dim3(64, 2), 256, 0, stream>>>(
        MX0b, 512, wb_xp1, 512, XX, 160, 160, 512, nullptr, nullptr, nullptr);

    // 3) mods + the 5 mixed GEMM inputs (K=32, vector fp32, bf16 out)
    k_gemm_mix5<<<dim3(128, 8, 5), 256, 0, stream>>>(XX, xp_w2, x_bias, Hb, AMXb);

    // 4) projections [MFMA]
    k_mgemm<ME_NONE><<<dim3(64, 2), 256, 0, stream>>>(
        AMXb + 0 * MD, 512, wb_r, 512, RQ, 256, 256, 512, nullptr, nullptr, nullptr);
    k_mgemm<ME_TANH_B16><<<dim3(64, 1), 256, 0, stream>>>(
        AMXb + 1 * MD, 512, wb_wA, 512, TAb, 64, 64, 512, nullptr, nullptr, nullptr);
    k_mgemm<ME_DECAY><<<dim3(64, 2), 256, 0, stream>>>(
        TAb, 64, wb_wB, 64, DEC, 256, 256, 64, w_b, nullptr, nullptr);
    k_mgemm<ME_NONE><<<dim3(64, 2), 256, 0, stream>>>(
        AMXb + 2 * MD, 512, wb_k, 512, KB, 256, 256, 512, nullptr, nullptr, nullptr);
    k_mgemm<ME_NONE><<<dim3(64, 4), 256, 0, stream>>>(
        AMXb + 3 * MD, 512, wb_v, 512, VB, 512, 512, 512, nullptr, nullptr, nullptr);
    k_mgemm<ME_NONE><<<dim3(64, 4), 256, 0, stream>>>(
        AMXb + 4 * MD, 512, wb_g, 512, GB, 512, 512, 512, nullptr, nullptr, nullptr);

    // 5) chunked scan (fp32)
    k_chunk_local<<<Bq * Hq * NCq, 128, 0, stream>>>(KB, DEC, VB, MC, PC);
    k_combine<<<(Bq * Hq * DKq * DVq) / 256, 256, 0, stream>>>(MC, PC, S0);
    k_chunk_out<<<Bq * Hq * NCq, 128, 0, stream>>>(RQ, KB, DEC, VB, S0, bonus, O);

    // 6) groupnorm + swish gate -> bf16, then output proj + residual [MFMA]
    k_gatenorm<<<Mq * Hq, 128, 0, stream>>>(O, GB, gn_g, gn_b, OBb);
    k_mgemm<ME_RESID><<<dim3(64, 4), 256, 0, stream>>>(
        OBb, 512, wb_o, 512, Z, 512, 512, 512, nullptr, R, nullptr);

    // 7) channel-mix FFN [MFMA]
    k_ln<<<Mq, 256, 0, stream>>>(Z, ln2_g, ln2_b, H2);
    k_mix2<<<Mq, 256, 0, stream>>>(H2, fk_mu, fr_mu, MXKb, MXRb);
    k_mgemm<ME_RELUSQ_B16><<<dim3(64, 8), 256, 0, stream>>>(
        MXKb, 512, wb_fk, 512, KKb, 1024, 1024, 512, nullptr, nullptr, nullptr);
    k_mgemm<ME_SIGMOID><<<dim3(64, 4), 256, 0, stream>>>(
        MXRb, 512, wb_fr, 512, RRb, 512, 512, 512, nullptr, nullptr, nullptr);
    k_mgemm<ME_GATED><<<dim3(64, 4), 256, 0, stream>>>(
        KKb, 1024, wb_fv, 1024, out, 512, 512, 1024, nullptr, Z, RRb);
}

// Round 5
// 468.747 us; speedup vs baseline: 1.3153x; 1.3153x over previous
//
#include <hip/hip_runtime.h>
#include <math.h>

// ---- problem constants (from reference) ----
constexpr int Bq = 4, Tq = 2048, Dq = 512, Hq = 4, DKq = 64, DVq = 128, LRq = 32;
constexpr int Mq = Bq * Tq;           // 8192 rows
constexpr float EPSq = 1e-5f;
// chunked scan: L=32 keeps decay dynamic range within fp32 (worst ~e^46)
constexpr int CL2 = 32, NC2 = Tq / CL2, BH2 = Bq * Hq;

typedef unsigned short u16;
typedef __attribute__((ext_vector_type(8))) short short8v;  // 8 bf16 (4 VGPR)
typedef __attribute__((ext_vector_type(4))) float f32x4;

// float -> bf16 (round-to-nearest-even)
__device__ __forceinline__ u16 f2b(float f) {
    unsigned u = __float_as_uint(f);
    u += 0x7fffu + ((u >> 16) & 1);
    return (u16)(u >> 16);
}

// async global->LDS, 16B per lane (dest = uniform base + lane*16)
__device__ __forceinline__ void gl_lds16(const void* g, void* l) {
    __builtin_amdgcn_global_load_lds(
        (const __attribute__((address_space(1))) unsigned int*)g,
        (__attribute__((address_space(3))) unsigned int*)l, 16, 0, 0);
}

// ============================================================
// LayerNorm kernels (fp32)
// ============================================================
__global__ __launch_bounds__(256)
void k_ln01(const float* __restrict__ x,
            const float* __restrict__ g0, const float* __restrict__ b0,
            const float* __restrict__ g1, const float* __restrict__ b1,
            float* __restrict__ Rout, float* __restrict__ Hout) {
    __shared__ float red[8];
    int row = blockIdx.x, tid = threadIdx.x;
    const float* xr = x + (size_t)row * Dq;
    float v0 = xr[tid], v1 = xr[tid + 256];

    float s = v0 + v1, q = v0 * v0 + v1 * v1;
#pragma unroll
    for (int o = 32; o; o >>= 1) { s += __shfl_down(s, o); q += __shfl_down(q, o); }
    if ((tid & 63) == 0) { red[tid >> 6] = s; red[4 + (tid >> 6)] = q; }
    __syncthreads();
    s = red[0] + red[1] + red[2] + red[3];
    q = red[4] + red[5] + red[6] + red[7];
    float mean = s * (1.f / Dq);
    float inv = rsqrtf(q * (1.f / Dq) - mean * mean + EPSq);
    float r0 = (v0 - mean) * inv * g0[tid] + b0[tid];
    float r1 = (v1 - mean) * inv * g0[tid + 256] + b0[tid + 256];
    Rout[(size_t)row * Dq + tid] = r0;
    Rout[(size_t)row * Dq + tid + 256] = r1;

    s = r0 + r1; q = r0 * r0 + r1 * r1;
#pragma unroll
    for (int o = 32; o; o >>= 1) { s += __shfl_down(s, o); q += __shfl_down(q, o); }
    __syncthreads();
    if ((tid & 63) == 0) { red[tid >> 6] = s; red[4 + (tid >> 6)] = q; }
    __syncthreads();
    s = red[0] + red[1] + red[2] + red[3];
    q = red[4] + red[5] + red[6] + red[7];
    mean = s * (1.f / Dq);
    inv = rsqrtf(q * (1.f / Dq) - mean * mean + EPSq);
    Hout[(size_t)row * Dq + tid] = (r0 - mean) * inv * g1[tid] + b1[tid];
    Hout[(size_t)row * Dq + tid + 256] = (r1 - mean) * inv * g1[tid + 256] + b1[tid + 256];
}

__global__ __launch_bounds__(256)
void k_ln(const float* __restrict__ in, const float* __restrict__ g,
          const float* __restrict__ b, float* __restrict__ out) {
    __shared__ float red[8];
    int row = blockIdx.x, tid = threadIdx.x;
    const float* xr = in + (size_t)row * Dq;
    float v0 = xr[tid], v1 = xr[tid + 256];
    float s = v0 + v1, q = v0 * v0 + v1 * v1;
#pragma unroll
    for (int o = 32; o; o >>= 1) { s += __shfl_down(s, o); q += __shfl_down(q, o); }
    if ((tid & 63) == 0) { red[tid >> 6] = s; red[4 + (tid >> 6)] = q; }
    __syncthreads();
    s = red[0] + red[1] + red[2] + red[3];
    q = red[4] + red[5] + red[6] + red[7];
    float mean = s * (1.f / Dq);
    float inv = rsqrtf(q * (1.f / Dq) - mean * mean + EPSq);
    out[(size_t)row * Dq + tid] = (v0 - mean) * inv * g[tid] + b[tid];
    out[(size_t)row * Dq + tid + 256] = (v1 - mean) * inv * g[tid + 256] + b[tid + 256];
}

// token-shift mix with constant mu vector: out = h + (shift(h)-h)*mu  -> bf16
__global__ __launch_bounds__(256)
void k_mix1(const float* __restrict__ h, const float* __restrict__ mu,
            u16* __restrict__ out) {
    int row = blockIdx.x, t = row % Tq;
    const float* hr = h + (size_t)row * Dq;
#pragma unroll
    for (int it = 0; it < 2; it++) {
        int d = threadIdx.x + it * 256;
        float hv = hr[d];
        float pv = t ? hr[d - Dq] : 0.f;
        out[(size_t)row * Dq + d] = f2b(hv + (pv - hv) * mu[d]);
    }
}

__global__ __launch_bounds__(256)
void k_mix2(const float* __restrict__ h, const float* __restrict__ muK,
            const float* __restrict__ muR, u16* __restrict__ outK,
            u16* __restrict__ outR) {
    int row = blockIdx.x, t = row % Tq;
    const float* hr = h + (size_t)row * Dq;
#pragma unroll
    for (int it = 0; it < 2; it++) {
        int d = threadIdx.x + it * 256;
        float hv = hr[d];
        float pv = t ? hr[d - Dq] : 0.f;
        float dl = pv - hv;
        outK[(size_t)row * Dq + d] = f2b(hv + dl * muK[d]);
        outR[(size_t)row * Dq + d] = f2b(hv + dl * muR[d]);
    }
}

// weight fp32 -> bf16 conversion (padded rows zeroed)
struct WConv {
    const float* src[11];
    u16* dst[11];
    int n[11];
    int npad[11];
};
__global__ __launch_bounds__(256)
void k_wconv(WConv wc) {
    int w = blockIdx.y;
    const float* s = wc.src[w];
    u16* d = wc.dst[w];
    int n = wc.n[w], np = wc.npad[w];
    for (int i = blockIdx.x * 256 + threadIdx.x; i < np; i += gridDim.x * 256)
        d[i] = (i < n) ? f2b(s[i]) : (u16)0;
}

// ============================================================
// bf16 MFMA GEMM: C[M,N] = epi( A[M,K](bf16) @ W[N,K](bf16)^T )
// 128x128 tile, BK=64, 4 waves (2x2), 4x4 16x16x32 frags/wave.
// ============================================================
enum MEpi { ME_NONE, ME_TANH_F32, ME_TANH_B16, ME_DECAY, ME_RESID,
            ME_RELUSQ_B16, ME_SIGMOID, ME_GATED };

template <int EPI>
__global__ __launch_bounds__(256)
void k_mgemm(const u16* __restrict__ A, int lda,
             const u16* __restrict__ W, int ldw,
             void* __restrict__ Cout, int ldc,
             int N, int K,
             const float* __restrict__ bias,   // DECAY: w_b
             const float* __restrict__ P1,     // RESID: residual ; GATED: z
             const float* __restrict__ P2) {   // GATED: rr
    __shared__ __align__(16) char smem[32768];   // sA 16KB | sB 16KB
    char* sA = smem;
    char* sB = smem + 16384;
    const int m0 = blockIdx.x * 128, n0 = blockIdx.y * 128;
    const int tid = threadIdx.x, lane = tid & 63, wid = tid >> 6;
    const int wm = wid >> 1, wn = wid & 1;     // 2x2 wave grid, 64x64 each

    f32x4 acc[4][4] = {};

    const int rl = lane >> 3;
    const int ccs = (lane & 7) ^ rl;
    const u16* ga = A + (size_t)(m0 + wid * 32 + rl) * lda + ccs * 8;
    const u16* gb = W + (size_t)(n0 + wid * 32 + rl) * ldw + ccs * 8;
    char* la = sA + (wid * 32) * 128;
    char* lb = sB + (wid * 32) * 128;

    const int nkt = K >> 6;
    for (int kt = 0; kt < nkt; ++kt) {
        const int k0 = kt << 6;
#pragma unroll
        for (int i = 0; i < 4; ++i) {
            gl_lds16(ga + (size_t)(i * 8) * lda + k0, la + i * 8 * 128);
            gl_lds16(gb + (size_t)(i * 8) * ldw + k0, lb + i * 8 * 128);
        }
        asm volatile("s_waitcnt vmcnt(0)" ::: "memory");
        __syncthreads();
#pragma unroll
        for (int ks = 0; ks < 2; ++ks) {
            short8v af[4], bfr[4];
            const int cc = ks * 4 + (lane >> 4);
#pragma unroll
            for (int i = 0; i < 4; ++i) {
                const int mr = wm * 64 + i * 16 + (lane & 15);
                af[i] = *(const short8v*)(sA + mr * 128 + ((cc ^ (mr & 7)) << 4));
                const int nr = wn * 64 + i * 16 + (lane & 15);
                bfr[i] = *(const short8v*)(sB + nr * 128 + ((cc ^ (nr & 7)) << 4));
            }
#pragma unroll
            for (int i = 0; i < 4; ++i)
#pragma unroll
                for (int j = 0; j < 4; ++j)
                    acc[i][j] = __builtin_amdgcn_mfma_f32_16x16x32_bf16(
                        af[i], bfr[j], acc[i][j], 0, 0, 0);
        }
        __syncthreads();
    }

    float* Cf = (float*)Cout;
    u16* Cb = (u16*)Cout;
#pragma unroll
    for (int i = 0; i < 4; ++i) {
        const int row = m0 + wm * 64 + i * 16 + (lane >> 4) * 4;
#pragma unroll
        for (int j = 0; j < 4; ++j) {
            const int col = n0 + wn * 64 + j * 16 + (lane & 15);
            if (col < N) {
#pragma unroll
                for (int r = 0; r < 4; ++r) {
                    const float v = acc[i][j][r];
                    const size_t idx = (size_t)(row + r) * ldc + col;
                    if constexpr (EPI == ME_NONE)        Cf[idx] = v;
                    else if constexpr (EPI == ME_TANH_F32) Cf[idx] = tanhf(v);
                    else if constexpr (EPI == ME_TANH_B16) Cb[idx] = f2b(tanhf(v));
                    else if constexpr (EPI == ME_DECAY)  Cf[idx] = expf(-expf(v + bias[col]));
                    else if constexpr (EPI == ME_RESID)  Cf[idx] = v + P1[idx];
                    else if constexpr (EPI == ME_RELUSQ_B16) {
                        float t = fmaxf(v, 0.f); Cb[idx] = f2b(t * t);
                    }
                    else if constexpr (EPI == ME_SIGMOID) Cf[idx] = 1.f / (1.f + __expf(-v));
                    else                                  Cf[idx] = P1[idx] + P2[idx] * v;
                }
            }
        }
    }
}

// ============================================================
// Fused 5-group LoRA-up GEMM (K=32, fp32 vector) + shift-mix epilogue -> bf16
// ============================================================
__global__ __launch_bounds__(256)
void k_gemm_mix5(const float* __restrict__ XX, const float* __restrict__ w2,
                 const float* __restrict__ xb, const float* __restrict__ Hb,
                 u16* __restrict__ AMX) {
    constexpr int BM = 64, BK = 16, K = LRq, LDX = 5 * LRq;
    __shared__ __align__(16) float sA[BK][BM + 4];
    __shared__ __align__(16) float sB[BK][BM + 4];
    int g = blockIdx.z;
    const float* A = XX + g * LRq;
    const float* W = w2 + g * LRq;
    const float* bias = xb + g * Dq;
    u16* C = AMX + (size_t)g * Mq * Dq;
    int m0 = blockIdx.x * BM, n0 = blockIdx.y * BM;
    int tid = threadIdx.x;
    int tx = tid & 15, ty = tid >> 4;
    int lr = tid >> 2, lc = (tid & 3) * 4;
    float acc[4][4] = {};

    for (int k0 = 0; k0 < K; k0 += BK) {
        float4 av = *(const float4*)(A + (size_t)(m0 + lr) * LDX + k0 + lc);
        float4 bv = *(const float4*)(W + (size_t)(n0 + lr) * LDX + k0 + lc);
        sA[lc + 0][lr] = av.x; sA[lc + 1][lr] = av.y;
        sA[lc + 2][lr] = av.z; sA[lc + 3][lr] = av.w;
        sB[lc + 0][lr] = bv.x; sB[lc + 1][lr] = bv.y;
        sB[lc + 2][lr] = bv.z; sB[lc + 3][lr] = bv.w;
        __syncthreads();
#pragma unroll
        for (int kk = 0; kk < BK; kk++) {
            float4 a4 = *(const float4*)&sA[kk][ty * 4];
            float4 b4 = *(const float4*)&sB[kk][tx * 4];
            acc[0][0] += a4.x * b4.x; acc[0][1] += a4.x * b4.y;
            acc[0][2] += a4.x * b4.z; acc[0][3] += a4.x * b4.w;
            acc[1][0] += a4.y * b4.x; acc[1][1] += a4.y * b4.y;
            acc[1][2] += a4.y * b4.z; acc[1][3] += a4.y * b4.w;
            acc[2][0] += a4.z * b4.x; acc[2][1] += a4.z * b4.y;
            acc[2][2] += a4.z * b4.z; acc[2][3] += a4.z * b4.w;
            acc[3][0] += a4.w * b4.x; acc[3][1] += a4.w * b4.y;
            acc[3][2] += a4.w * b4.z; acc[3][3] += a4.w * b4.w;
        }
        __syncthreads();
    }

#pragma unroll
    for (int i = 0; i < 4; i++) {
        int row = m0 + ty * 4 + i;
        int t = row % Tq;
#pragma unroll
        for (int j = 0; j < 4; j++) {
            int col = n0 + tx * 4 + j;
            size_t idx = (size_t)row * Dq + col;
            float val = acc[i][j] + bias[col];
            float hv = Hb[idx];
            float pv = t ? Hb[idx - Dq] : 0.f;
            C[idx] = f2b(hv + (pv - hv) * val);
        }
    }
}

// ============================================================
// Chunked matmul scan (L=32).  Definitions per chunk:
//   Dprev_t = prod_{u<t} d_u, Dc_t = prod_{u<=t} d_u, P = Dc_{L-1}
//   RQ = r*Dprev, KQ = k/Dc, DIAG_t = sum_k r*k*bonus
//   M = P (x) (KQ^T @ V)  ;  S0 recursion: s <- P*s + M
//   O[t] = sum_{s<t} (RQ_t . KQ_s) V[s] + DIAG_t V[t] + RQ_t @ S0
// ============================================================
__global__ __launch_bounds__(256)
void k_prep_m(const float* __restrict__ Rp, const float* __restrict__ Kp,
              const float* __restrict__ Dp, const float* __restrict__ Vp,
              const float* __restrict__ bonus,
              float* __restrict__ RQd, float* __restrict__ KQg,
              float* __restrict__ DIAG, float* __restrict__ PC,
              float* __restrict__ MC) {
    int c = blockIdx.x, bh = blockIdx.y;
    int b = bh >> 2, h = bh & 3;
    __shared__ float Rl[CL2][68], Kl[CL2][68], Dl[CL2][68];
    __shared__ float Vl[CL2][128];
    __shared__ float Pl[64];
    int tid = threadIdx.x;
#pragma unroll
    for (int i = 0; i < 8; i++) {
        int idx = i * 256 + tid;
        int t = idx >> 6, k = idx & 63;
        size_t g = ((size_t)(b * Tq + c * CL2 + t) * Hq + h) * DKq + k;
        Rl[t][k] = Rp[g]; Kl[t][k] = Kp[g]; Dl[t][k] = Dp[g];
    }
#pragma unroll
    for (int i = 0; i < 16; i++) {
        int idx = i * 256 + tid;
        int t = idx >> 7, v = idx & 127;
        Vl[t][v] = Vp[((size_t)(b * Tq + c * CL2 + t) * Hq + h) * DVq + v];
    }
    __syncthreads();
    // DIAG (uses original r,k — before prefix overwrites)
    {
        int t = tid >> 3, kg = tid & 7;
        float p = 0.f;
#pragma unroll
        for (int i = 0; i < 8; i++) {
            int k = kg * 8 + i;
            p += Rl[t][k] * Kl[t][k] * bonus[h * DKq + k];
        }
        p += __shfl_down(p, 4, 8);
        p += __shfl_down(p, 2, 8);
        p += __shfl_down(p, 1, 8);
        if (kg == 0) DIAG[(size_t)bh * Tq + c * CL2 + t] = p;
    }
    __syncthreads();
    // per-channel serial prefix products (threads 0..63, lane=k: conflict-free)
    if (tid < 64) {
        int k = tid;
        float p = 1.f;
        for (int t = 0; t < CL2; t++) {
            float d = Dl[t][k];
            Rl[t][k] *= p;       // r * Dprev
            p *= d;
            Kl[t][k] /= p;       // k / Dc
        }
        Pl[k] = p;
    }
    __syncthreads();
    // store RQ, KQ ([bh][T][64] layout, coalesced)
#pragma unroll
    for (int i = 0; i < 8; i++) {
        int idx = i * 256 + tid;
        int t = idx >> 6, k = idx & 63;
        size_t g = ((size_t)bh * Tq + c * CL2 + t) * DKq + k;
        RQd[g] = Rl[t][k];
        KQg[g] = Kl[t][k];
    }
    if (tid < 64) PC[(size_t)(bh * NC2 + c) * DKq + tid] = Pl[tid];
    // M = P (x) (KQ^T @ V): thread (tk,tv) -> 8 k's x 4 v's
    {
        int tk = tid >> 5, tv = tid & 31;
        float acc[8][4] = {};
        for (int t = 0; t < CL2; t++) {
            float4 ka = *(const float4*)&Kl[t][tk * 8];
            float4 kb = *(const float4*)&Kl[t][tk * 8 + 4];
            float4 v4 = *(const float4*)&Vl[t][tv * 4];
            float kv[8] = {ka.x, ka.y, ka.z, ka.w, kb.x, kb.y, kb.z, kb.w};
#pragma unroll
            for (int i = 0; i < 8; i++) {
                acc[i][0] = fmaf(kv[i], v4.x, acc[i][0]);
                acc[i][1] = fmaf(kv[i], v4.y, acc[i][1]);
                acc[i][2] = fmaf(kv[i], v4.z, acc[i][2]);
                acc[i][3] = fmaf(kv[i], v4.w, acc[i][3]);
            }
        }
#pragma unroll
        for (int i = 0; i < 8; i++) {
            int k = tk * 8 + i;
            float P = Pl[k];
            *(float4*)&MC[((size_t)(bh * NC2 + c) * DKq + k) * DVq + tv * 4] =
                make_float4(acc[i][0] * P, acc[i][1] * P, acc[i][2] * P, acc[i][3] * P);
        }
    }
}

// cross-chunk combine, in place: buffer enters holding M_c, exits holding S0_c
__global__ __launch_bounds__(256)
void k_combine2(float* __restrict__ S0MC, const float* __restrict__ PC) {
    int idx = blockIdx.x * 256 + threadIdx.x;   // (bh,k,v)
    int v = idx & 127;
    int k = (idx >> 7) & 63;
    int bh = idx >> 13;
    float s = 0.f;
    for (int c = 0; c < NC2; c++) {
        size_t p = (size_t)(bh * NC2 + c) * DKq + k;
        size_t m = p * DVq + v;
        float mc = S0MC[m];
        S0MC[m] = s;
        s = fmaf(PC[p], s, mc);
    }
}

__global__ __launch_bounds__(256)
void k_scan_o(const float* __restrict__ RQd, const float* __restrict__ KQg,
              const float* __restrict__ Vp, const float* __restrict__ S0,
              const float* __restrict__ DIAG, float* __restrict__ O) {
    int c = blockIdx.x, bh = blockIdx.y;
    int b = bh >> 2, h = bh & 3;
    __shared__ float RQl[CL2][68];
    __shared__ float KQt[DKq][36];     // transposed: KQt[k][s]
    __shared__ float Vl[CL2][128];
    __shared__ float S0l[DKq][128];
    __shared__ float Al[CL2][33];
    int tid = threadIdx.x;
#pragma unroll
    for (int i = 0; i < 8; i++) {
        int idx = i * 256 + tid;
        int t = idx >> 6, k = idx & 63;
        size_t g = ((size_t)bh * Tq + c * CL2 + t) * DKq + k;
        RQl[t][k] = RQd[g];
        KQt[k][t] = KQg[g];
    }
#pragma unroll
    for (int i = 0; i < 16; i++) {
        int idx = i * 256 + tid;
        int t = idx >> 7, v = idx & 127;
        Vl[t][v] = Vp[((size_t)(b * Tq + c * CL2 + t) * Hq + h) * DVq + v];
    }
#pragma unroll
    for (int i = 0; i < 32; i++) {
        int idx = i * 256 + tid;
        int k = idx >> 7, v = idx & 127;
        S0l[k][v] = S0[((size_t)(bh * NC2 + c) * DKq + k) * DVq + v];
    }
    __syncthreads();
    // A stage: thread (t, sq) -> A[t][sq*4..+3]
    {
        int t = tid >> 3, sq = tid & 7;
        float a[4] = {};
        for (int k = 0; k < DKq; k++) {
            float rq = RQl[t][k];
            float4 k4 = *(const float4*)&KQt[k][sq * 4];
            a[0] = fmaf(rq, k4.x, a[0]);
            a[1] = fmaf(rq, k4.y, a[1]);
            a[2] = fmaf(rq, k4.z, a[2]);
            a[3] = fmaf(rq, k4.w, a[3]);
        }
        float diag = DIAG[(size_t)bh * Tq + c * CL2 + t];
#pragma unroll
        for (int j = 0; j < 4; j++) {
            int s = sq * 4 + j;
            Al[t][s] = (s < t) ? a[j] : (s == t ? diag : 0.f);
        }
    }
    __syncthreads();
    // O stage: thread (t, vg) -> v in {vg*4+q*32}, q=0..3
    {
        int t = tid >> 3, vg = tid & 7;
        float o[16] = {};
        for (int s = 0; s <= t; s++) {
            float a = Al[t][s];
#pragma unroll
            for (int q = 0; q < 4; q++) {
                float4 v4 = *(const float4*)&Vl[s][vg * 4 + q * 32];
                o[q * 4 + 0] = fmaf(a, v4.x, o[q * 4 + 0]);
                o[q * 4 + 1] = fmaf(a, v4.y, o[q * 4 + 1]);
                o[q * 4 + 2] = fmaf(a, v4.z, o[q * 4 + 2]);
                o[q * 4 + 3] = fmaf(a, v4.w, o[q * 4 + 3]);
            }
        }
        for (int k = 0; k < DKq; k++) {
            float rq = RQl[t][k];
#pragma unroll
            for (int q = 0; q < 4; q++) {
                float4 s4 = *(const float4*)&S0l[k][vg * 4 + q * 32];
                o[q * 4 + 0] = fmaf(rq, s4.x, o[q * 4 + 0]);
                o[q * 4 + 1] = fmaf(rq, s4.y, o[q * 4 + 1]);
                o[q * 4 + 2] = fmaf(rq, s4.z, o[q * 4 + 2]);
                o[q * 4 + 3] = fmaf(rq, s4.w, o[q * 4 + 3]);
            }
        }
        size_t gb = ((size_t)(b * Tq + c * CL2 + t) * Hq + h) * DVq;
#pragma unroll
        for (int q = 0; q < 4; q++)
            *(float4*)&O[gb + vg * 4 + q * 32] =
                make_float4(o[q * 4], o[q * 4 + 1], o[q * 4 + 2], o[q * 4 + 3]);
    }
}

// per-head groupnorm + swish gate -> bf16
__global__ __launch_bounds__(128)
void k_gatenorm(const float* __restrict__ O, const float* __restrict__ G,
                const float* __restrict__ gn_g, const float* __restrict__ gn_b,
                u16* __restrict__ OB) {
    int r = blockIdx.x;  // (b,t,h)
    size_t base = (size_t)r * DVq;
    int tid = threadIdx.x;
    float v = O[base + tid];
    float s = v, q = v * v;
#pragma unroll
    for (int o = 32; o; o >>= 1) { s += __shfl_down(s, o); q += __shfl_down(q, o); }
    __shared__ float tmp[4];
    int lane = tid & 63, wid = tid >> 6;
    if (lane == 0) { tmp[wid] = s; tmp[wid + 2] = q; }
    __syncthreads();
    s = tmp[0] + tmp[1]; q = tmp[2] + tmp[3];
    float mean = s * (1.f / DVq);
    float inv = rsqrtf(q * (1.f / DVq) - mean * mean + EPSq);
    float ln = (v - mean) * inv * gn_g[tid] + gn_b[tid];
    float g = G[base + tid];
    OB[base + tid] = f2b(ln * (g / (1.f + __expf(-g))));
}

// ============================================================
// Host-side launch
// ============================================================
extern "C" void kernel_launch(void* const* d_in, const int* in_sizes, int n_in,
                              void* d_out, int out_size, void* d_ws, size_t ws_size,
                              hipStream_t stream) {
    const float* x     = (const float*)d_in[0];
    const float* ln0_g = (const float*)d_in[1];
    const float* ln0_b = (const float*)d_in[2];
    const float* ln1_g = (const float*)d_in[3];
    const float* ln1_b = (const float*)d_in[4];
    const float* ln2_g = (const float*)d_in[5];
    const float* ln2_b = (const float*)d_in[6];
    const float* xp_mu = (const float*)d_in[7];
    const float* xp_w1 = (const float*)d_in[8];   // (160,512)
    const float* xp_w2 = (const float*)d_in[9];   // (512,160)
    const float* x_bias= (const float*)d_in[10];  // (5,512)
    const float* r_w   = (const float*)d_in[11];  // (256,512)
    const float* w_A   = (const float*)d_in[12];  // (64,512)
    const float* w_B   = (const float*)d_in[13];  // (256,64)
    const float* w_b   = (const float*)d_in[14];  // (256)
    const float* k_w   = (const float*)d_in[15];  // (256,512)
    const float* v_w   = (const float*)d_in[16];  // (512,512)
    const float* g_w   = (const float*)d_in[17];  // (512,512)
    const float* bonus = (const float*)d_in[18];  // (4,64)
    const float* gn_g  = (const float*)d_in[19];  // (128)
    const float* gn_b  = (const float*)d_in[20];
    const float* o_w   = (const float*)d_in[21];  // (512,512)
    const float* fk_mu = (const float*)d_in[22];
    const float* fk_w  = (const float*)d_in[23];  // (1024,512)
    const float* fr_mu = (const float*)d_in[24];
    const float* fr_w  = (const float*)d_in[25];  // (512,512)
    const float* fv_w  = (const float*)d_in[26];  // (512,1024)
    float* out = (float*)d_out;
    (void)in_sizes; (void)n_in; (void)out_size; (void)ws_size;

    const size_t MD = (size_t)Mq * Dq;  // 4M elems
    float* ws = (float*)d_ws;
    size_t off = 0;
    auto af32 = [&](size_t n) { float* p = ws + off; off += n; return p; };

    float* R    = af32(MD);                 // ln0 out (residual), live to o-GEMM
    float* Hb   = af32(MD);                 // ln1 out, live to mix5
    float* XX   = af32((size_t)Mq * 160);   // lora-down (fp32, mix5 A operand)
    float* Rproj= af32((size_t)Mq * 256);
    float* DEC  = af32((size_t)Mq * 256);
    float* KB   = af32((size_t)Mq * 256);
    float* VB   = af32(MD);
    float* GB   = af32(MD);
    float* PC   = af32((size_t)BH2 * NC2 * DKq);         // 64K
    float* S0MC = af32((size_t)BH2 * NC2 * DKq * DVq);   // 8.39M (M_c then S0, in place)
    float* DIAG = af32((size_t)BH2 * Tq);                // 32K

    u16* us = (u16*)(ws + off);
    size_t uo = 0;
    auto au16 = [&](size_t n) { u16* p = us + uo; uo += n; return p; };
    u16* MX0b = au16(MD);          // mix(h,xp_mu) bf16
    u16* AMXb = au16(5 * MD);      // 5 mixed GEMM inputs bf16
    u16* TAb  = au16((size_t)Mq * 64);
    u16* OBb  = au16(MD);          // gatenorm out bf16
    u16* wb_xp1 = au16(256 * 512); // padded 160->256 rows
    u16* wb_r   = au16(256 * 512);
    u16* wb_wA  = au16(128 * 512); // padded 64->128 rows
    u16* wb_wB  = au16(256 * 64);
    u16* wb_k   = au16(256 * 512);
    u16* wb_v   = au16(512 * 512);
    u16* wb_g   = au16(512 * 512);
    u16* wb_o   = au16(512 * 512);
    u16* wb_fk  = au16(1024 * 512);
    u16* wb_fr  = au16(512 * 512);
    u16* wb_fv  = au16(512 * 1024);

    // lifetime-checked aliases (stream-ordered, all disjoint in time):
    float* RQd = (float*)MX0b;            // 2M f32 = 4M u16 ; MX0b dead after xp1-GEMM
    float* KQg = (float*)(AMXb + 4 * MD); // slice 4 dead after g-GEMM
    float* O   = (float*)(AMXb + 2 * MD); // slices 2+3 dead after k/v-GEMMs
    float* H2  = O;                        // ln2 out  (O dead after gatenorm)
    float* Z   = GB;                       // a+residual (GB dead after gatenorm)
    float* RRb = VB;                       // sigmoid gate (VB dead after scan)
    u16* MXKb = AMXb;                      // slice 0 (dead after r-GEMM)
    u16* MXRb = AMXb + MD;                 // slice 1 (dead after wA-GEMM)
    u16* KKb  = AMXb + 2 * MD;             // slices 2+3 (H2 dead before fk-GEMM)

    // 0) weights -> bf16
    WConv wc;
    const float* wsrc[11] = {xp_w1, r_w, w_A, w_B, k_w, v_w, g_w, o_w, fk_w, fr_w, fv_w};
    u16* wdst[11] = {wb_xp1, wb_r, wb_wA, wb_wB, wb_k, wb_v, wb_g, wb_o, wb_fk, wb_fr, wb_fv};
    int wn_[11]  = {160*512, 256*512, 64*512, 256*64, 256*512, 512*512, 512*512,
                    512*512, 1024*512, 512*512, 512*1024};
    int wnp[11]  = {256*512, 256*512, 128*512, 256*64, 256*512, 512*512, 512*512,
                    512*512, 1024*512, 512*512, 512*1024};
    for (int i = 0; i < 11; i++) { wc.src[i] = wsrc[i]; wc.dst[i] = wdst[i];
                                   wc.n[i] = wn_[i]; wc.npad[i] = wnp[i]; }
    k_wconv<<<dim3(64, 11), 256, 0, stream>>>(wc);

    // 1) pre-norms
    k_ln01<<<Mq, 256, 0, stream>>>(x, ln0_g, ln0_b, ln1_g, ln1_b, R, Hb);

    // 2) xx = tanh(mix(h, xp_mu) @ xp_w1^T)   [MFMA]
    k_mix1<<<Mq, 256, 0, stream>>>(Hb, xp_mu, MX0b);
    k_mgemm<ME_TANH_F32><<<dim3(64, 2), 256, 0, stream>>>(
        MX0b, 512, wb_xp1, 512, XX, 160, 160, 512, nullptr, nullptr, nullptr);

    // 3) mods + the 5 mixed GEMM inputs (K=32, vector fp32, bf16 out)
    k_gemm_mix5<<<dim3(128, 8, 5), 256, 0, stream>>>(XX, xp_w2, x_bias, Hb, AMXb);

    // 4) projections [MFMA]
    k_mgemm<ME_NONE><<<dim3(64, 2), 256, 0, stream>>>(
        AMXb + 0 * MD, 512, wb_r, 512, Rproj, 256, 256, 512, nullptr, nullptr, nullptr);
    k_mgemm<ME_TANH_B16><<<dim3(64, 1), 256, 0, stream>>>(
        AMXb + 1 * MD, 512, wb_wA, 512, TAb, 64, 64, 512, nullptr, nullptr, nullptr);
    k_mgemm<ME_DECAY><<<dim3(64, 2), 256, 0, stream>>>(
        TAb, 64, wb_wB, 64, DEC, 256, 256, 64, w_b, nullptr, nullptr);
    k_mgemm<ME_NONE><<<dim3(64, 2), 256, 0, stream>>>(
        AMXb + 2 * MD, 512, wb_k, 512, KB, 256, 256, 512, nullptr, nullptr, nullptr);
    k_mgemm<ME_NONE><<<dim3(64, 4), 256, 0, stream>>>(
        AMXb + 3 * MD, 512, wb_v, 512, VB, 512, 512, 512, nullptr, nullptr, nullptr);
    k_mgemm<ME_NONE><<<dim3(64, 4), 256, 0, stream>>>(
        AMXb + 4 * MD, 512, wb_g, 512, GB, 512, 512, 512, nullptr, nullptr, nullptr);

    // 5) chunked matmul scan
    k_prep_m<<<dim3(NC2, BH2), 256, 0, stream>>>(Rproj, KB, DEC, VB, bonus,
                                                 RQd, KQg, DIAG, PC, S0MC);
    k_combine2<<<(BH2 * DKq * DVq) / 256, 256, 0, stream>>>(S0MC, PC);
    k_scan_o<<<dim3(NC2, BH2), 256, 0, stream>>>(RQd, KQg, VB, S0MC, DIAG, O);

    // 6) groupnorm + swish gate -> bf16, then output proj + residual [MFMA]
    k_gatenorm<<<Mq * Hq, 128, 0, stream>>>(O, GB, gn_g, gn_b, OBb);
    k_mgemm<ME_RESID><<<dim3(64, 4), 256, 0, stream>>>(
        OBb, 512, wb_o, 512, Z, 512, 512, 512, nullptr, R, nullptr);

    // 7) channel-mix FFN [MFMA]
    k_ln<<<Mq, 256, 0, stream>>>(Z, ln2_g, ln2_b, H2);
    k_mix2<<<Mq, 256, 0, stream>>>(H2, fk_mu, fr_mu, MXKb, MXRb);
    k_mgemm<ME_RELUSQ_B16><<<dim3(64, 8), 256, 0, stream>>>(
        MXKb, 512, wb_fk, 512, KKb, 1024, 1024, 512, nullptr, nullptr, nullptr);
    k_mgemm<ME_SIGMOID><<<dim3(64, 4), 256, 0, stream>>>(
        MXRb, 512, wb_fr, 512, RRb, 512, 512, 512, nullptr, nullptr, nullptr);
    k_mgemm<ME_GATED><<<dim3(64, 4), 256, 0, stream>>>(
        KKb, 1024, wb_fv, 1024, out, 512, 512, 1024, nullptr, Z, RRb);
}

// Round 8
// 432.565 us; speedup vs baseline: 1.4254x; 1.0836x over previous
//
#include <hip/hip_runtime.h>
#include <math.h>

// ---- problem constants (from reference) ----
constexpr int Bq = 4, Tq = 2048, Dq = 512, Hq = 4, DKq = 64, DVq = 128, LRq = 32;
constexpr int Mq = Bq * Tq;           // 8192 rows
constexpr float EPSq = 1e-5f;
// chunked scan: L=32 keeps decay dynamic range within fp32 (worst ~e^46)
constexpr int CL2 = 32, NC2 = Tq / CL2, BH2 = Bq * Hq;

typedef unsigned short u16;
typedef __attribute__((ext_vector_type(8))) short short8v;  // 8 bf16 (4 VGPR)
typedef __attribute__((ext_vector_type(4))) float f32x4;

// float -> bf16 (round-to-nearest-even)
__device__ __forceinline__ u16 f2b(float f) {
    unsigned u = __float_as_uint(f);
    u += 0x7fffu + ((u >> 16) & 1);
    return (u16)(u >> 16);
}

// async global->LDS, 16B per lane (dest = uniform base + lane*16)
__device__ __forceinline__ void gl_lds16(const void* g, void* l) {
    __builtin_amdgcn_global_load_lds(
        (const __attribute__((address_space(1))) unsigned int*)g,
        (__attribute__((address_space(3))) unsigned int*)l, 16, 0, 0);
}

// ============================================================
// LayerNorm kernels (fp32)
// ============================================================
__global__ __launch_bounds__(256)
void k_ln01(const float* __restrict__ x,
            const float* __restrict__ g0, const float* __restrict__ b0,
            const float* __restrict__ g1, const float* __restrict__ b1,
            float* __restrict__ Rout, float* __restrict__ Hout) {
    __shared__ float red[8];
    int row = blockIdx.x, tid = threadIdx.x;
    const float* xr = x + (size_t)row * Dq;
    float v0 = xr[tid], v1 = xr[tid + 256];

    float s = v0 + v1, q = v0 * v0 + v1 * v1;
#pragma unroll
    for (int o = 32; o; o >>= 1) { s += __shfl_down(s, o); q += __shfl_down(q, o); }
    if ((tid & 63) == 0) { red[tid >> 6] = s; red[4 + (tid >> 6)] = q; }
    __syncthreads();
    s = red[0] + red[1] + red[2] + red[3];
    q = red[4] + red[5] + red[6] + red[7];
    float mean = s * (1.f / Dq);
    float inv = rsqrtf(q * (1.f / Dq) - mean * mean + EPSq);
    float r0 = (v0 - mean) * inv * g0[tid] + b0[tid];
    float r1 = (v1 - mean) * inv * g0[tid + 256] + b0[tid + 256];
    Rout[(size_t)row * Dq + tid] = r0;
    Rout[(size_t)row * Dq + tid + 256] = r1;

    s = r0 + r1; q = r0 * r0 + r1 * r1;
#pragma unroll
    for (int o = 32; o; o >>= 1) { s += __shfl_down(s, o); q += __shfl_down(q, o); }
    __syncthreads();
    if ((tid & 63) == 0) { red[tid >> 6] = s; red[4 + (tid >> 6)] = q; }
    __syncthreads();
    s = red[0] + red[1] + red[2] + red[3];
    q = red[4] + red[5] + red[6] + red[7];
    mean = s * (1.f / Dq);
    inv = rsqrtf(q * (1.f / Dq) - mean * mean + EPSq);
    Hout[(size_t)row * Dq + tid] = (r0 - mean) * inv * g1[tid] + b1[tid];
    Hout[(size_t)row * Dq + tid + 256] = (r1 - mean) * inv * g1[tid + 256] + b1[tid + 256];
}

// token-shift mix with constant mu vector: out = h + (shift(h)-h)*mu  -> bf16
__global__ __launch_bounds__(256)
void k_mix1(const float* __restrict__ h, const float* __restrict__ mu,
            u16* __restrict__ out) {
    int row = blockIdx.x, t = row % Tq;
    const float* hr = h + (size_t)row * Dq;
#pragma unroll
    for (int it = 0; it < 2; it++) {
        int d = threadIdx.x + it * 256;
        float hv = hr[d];
        float pv = t ? hr[d - Dq] : 0.f;
        out[(size_t)row * Dq + d] = f2b(hv + (pv - hv) * mu[d]);
    }
}

// fused ln2 + token-shift mix (recomputes row-1's LN; eliminates H2 buffer)
__global__ __launch_bounds__(256)
void k_ln2mix(const float* __restrict__ Z,
              const float* __restrict__ g2, const float* __restrict__ b2,
              const float* __restrict__ muK, const float* __restrict__ muR,
              u16* __restrict__ outK, u16* __restrict__ outR) {
    __shared__ float red[16];
    int row = blockIdx.x, t = row % Tq, tid = threadIdx.x;
    const float* zr = Z + (size_t)row * Dq;
    float c0 = zr[tid], c1 = zr[tid + 256];
    float p0 = 0.f, p1 = 0.f;
    if (t) { p0 = zr[tid - Dq]; p1 = zr[tid + 256 - Dq]; }
    float sc = c0 + c1, qc = c0 * c0 + c1 * c1;
    float sp = p0 + p1, qp = p0 * p0 + p1 * p1;
#pragma unroll
    for (int o = 32; o; o >>= 1) {
        sc += __shfl_down(sc, o); qc += __shfl_down(qc, o);
        sp += __shfl_down(sp, o); qp += __shfl_down(qp, o);
    }
    if ((tid & 63) == 0) {
        int w = tid >> 6;
        red[w] = sc; red[4 + w] = qc; red[8 + w] = sp; red[12 + w] = qp;
    }
    __syncthreads();
    sc = red[0] + red[1] + red[2] + red[3];
    qc = red[4] + red[5] + red[6] + red[7];
    sp = red[8] + red[9] + red[10] + red[11];
    qp = red[12] + red[13] + red[14] + red[15];
    float mc = sc * (1.f / Dq), ic = rsqrtf(qc * (1.f / Dq) - mc * mc + EPSq);
    float mp = sp * (1.f / Dq), ip = rsqrtf(qp * (1.f / Dq) - mp * mp + EPSq);
#pragma unroll
    for (int it = 0; it < 2; it++) {
        int d = tid + it * 256;
        float cv = it ? c1 : c0, pv = it ? p1 : p0;
        float hc = (cv - mc) * ic * g2[d] + b2[d];
        float hp = t ? ((pv - mp) * ip * g2[d] + b2[d]) : 0.f;
        float dl = hp - hc;
        outK[(size_t)row * Dq + d] = f2b(hc + dl * muK[d]);
        outR[(size_t)row * Dq + d] = f2b(hc + dl * muR[d]);
    }
}

// weight fp32 -> bf16 conversion (padded rows zeroed)
struct WConv {
    const float* src[11];
    u16* dst[11];
    int n[11];
    int npad[11];
};
__global__ __launch_bounds__(256)
void k_wconv(WConv wc) {
    int w = blockIdx.y;
    const float* s = wc.src[w];
    u16* d = wc.dst[w];
    int n = wc.n[w], np = wc.npad[w];
    for (int i = blockIdx.x * 256 + threadIdx.x; i < np; i += gridDim.x * 256)
        d[i] = (i < n) ? f2b(s[i]) : (u16)0;
}

// ============================================================
// bf16 MFMA GEMM core: 128x128 tile, BK=64, 4 waves (2x2),
// 4x4 16x16x32 frags/wave, global_load_lds staging, XOR-swizzled LDS.
// ============================================================
enum MEpi { ME_NONE, ME_TANH_F32, ME_TANH_B16, ME_DECAY, ME_RESID,
            ME_RELUSQ_B16, ME_SIGMOID, ME_GATED };

template <int EPI>
__global__ __launch_bounds__(256)
void k_mgemm(const u16* __restrict__ A, int lda,
             const u16* __restrict__ W, int ldw,
             void* __restrict__ Cout, int ldc,
             int N, int K,
             const float* __restrict__ bias,   // DECAY: w_b
             const float* __restrict__ P1,     // RESID: residual ; GATED: z
             const float* __restrict__ P2) {   // GATED: rr
    __shared__ __align__(16) char smem[32768];   // sA 16KB | sB 16KB
    char* sA = smem;
    char* sB = smem + 16384;
    const int m0 = blockIdx.x * 128, n0 = blockIdx.y * 128;
    const int tid = threadIdx.x, lane = tid & 63, wid = tid >> 6;
    const int wm = wid >> 1, wn = wid & 1;     // 2x2 wave grid, 64x64 each

    f32x4 acc[4][4] = {};

    const int rl = lane >> 3;
    const int ccs = (lane & 7) ^ rl;
    const u16* ga = A + (size_t)(m0 + wid * 32 + rl) * lda + ccs * 8;
    const u16* gb = W + (size_t)(n0 + wid * 32 + rl) * ldw + ccs * 8;
    char* la = sA + (wid * 32) * 128;
    char* lb = sB + (wid * 32) * 128;

    const int nkt = K >> 6;
    for (int kt = 0; kt < nkt; ++kt) {
        const int k0 = kt << 6;
#pragma unroll
        for (int i = 0; i < 4; ++i) {
            gl_lds16(ga + (size_t)(i * 8) * lda + k0, la + i * 8 * 128);
            gl_lds16(gb + (size_t)(i * 8) * ldw + k0, lb + i * 8 * 128);
        }
        asm volatile("s_waitcnt vmcnt(0)" ::: "memory");
        __syncthreads();
#pragma unroll
        for (int ks = 0; ks < 2; ++ks) {
            short8v af[4], bfr[4];
            const int cc = ks * 4 + (lane >> 4);
#pragma unroll
            for (int i = 0; i < 4; ++i) {
                const int mr = wm * 64 + i * 16 + (lane & 15);
                af[i] = *(const short8v*)(sA + mr * 128 + ((cc ^ (mr & 7)) << 4));
                const int nr = wn * 64 + i * 16 + (lane & 15);
                bfr[i] = *(const short8v*)(sB + nr * 128 + ((cc ^ (nr & 7)) << 4));
            }
#pragma unroll
            for (int i = 0; i < 4; ++i)
#pragma unroll
                for (int j = 0; j < 4; ++j)
                    acc[i][j] = __builtin_amdgcn_mfma_f32_16x16x32_bf16(
                        af[i], bfr[j], acc[i][j], 0, 0, 0);
        }
        __syncthreads();
    }

    float* Cf = (float*)Cout;
    u16* Cb = (u16*)Cout;
#pragma unroll
    for (int i = 0; i < 4; ++i) {
        const int row = m0 + wm * 64 + i * 16 + (lane >> 4) * 4;
#pragma unroll
        for (int j = 0; j < 4; ++j) {
            const int col = n0 + wn * 64 + j * 16 + (lane & 15);
            if (col < N) {
#pragma unroll
                for (int r = 0; r < 4; ++r) {
                    const float v = acc[i][j][r];
                    const size_t idx = (size_t)(row + r) * ldc + col;
                    if constexpr (EPI == ME_NONE)        Cf[idx] = v;
                    else if constexpr (EPI == ME_TANH_F32) Cf[idx] = tanhf(v);
                    else if constexpr (EPI == ME_TANH_B16) Cb[idx] = f2b(tanhf(v));
                    else if constexpr (EPI == ME_DECAY)  Cf[idx] = expf(-expf(v + bias[col]));
                    else if constexpr (EPI == ME_RESID)  Cf[idx] = v + P1[idx];
                    else if constexpr (EPI == ME_RELUSQ_B16) {
                        float t = fmaxf(v, 0.f); Cb[idx] = f2b(t * t);
                    }
                    else if constexpr (EPI == ME_SIGMOID) Cf[idx] = 1.f / (1.f + __expf(-v));
                    else                                  Cf[idx] = P1[idx] + P2[idx] * v;
                }
            }
        }
    }
}

// ---- batched heterogeneous MFMA GEMM: one launch, many sub-GEMMs ----
struct GemmDesc {
    const u16* A; const u16* W; void* C;
    int lda, ldw, ldc, N, K, epi;   // epi: 0 NONE(f32) 1 TANH_B16 2 RELUSQ_B16 3 SIGMOID(f32)
};
struct MultiDesc {
    GemmDesc g[5];
    int gid[16];     // blockIdx.y -> gemm id
    int ntile[16];   // blockIdx.y -> n-tile within gemm
};

__global__ __launch_bounds__(256)
void k_mgemm_multi(MultiDesc md) {
    __shared__ __align__(16) char smem[32768];
    char* sA = smem;
    char* sB = smem + 16384;
    const GemmDesc d = md.g[md.gid[blockIdx.y]];
    const int m0 = blockIdx.x * 128, n0 = md.ntile[blockIdx.y] * 128;
    const int tid = threadIdx.x, lane = tid & 63, wid = tid >> 6;
    const int wm = wid >> 1, wn = wid & 1;

    f32x4 acc[4][4] = {};

    const int rl = lane >> 3;
    const int ccs = (lane & 7) ^ rl;
    const u16* ga = d.A + (size_t)(m0 + wid * 32 + rl) * d.lda + ccs * 8;
    const u16* gb = d.W + (size_t)(n0 + wid * 32 + rl) * d.ldw + ccs * 8;
    char* la = sA + (wid * 32) * 128;
    char* lb = sB + (wid * 32) * 128;

    const int nkt = d.K >> 6;
    for (int kt = 0; kt < nkt; ++kt) {
        const int k0 = kt << 6;
#pragma unroll
        for (int i = 0; i < 4; ++i) {
            gl_lds16(ga + (size_t)(i * 8) * d.lda + k0, la + i * 8 * 128);
            gl_lds16(gb + (size_t)(i * 8) * d.ldw + k0, lb + i * 8 * 128);
        }
        asm volatile("s_waitcnt vmcnt(0)" ::: "memory");
        __syncthreads();
#pragma unroll
        for (int ks = 0; ks < 2; ++ks) {
            short8v af[4], bfr[4];
            const int cc = ks * 4 + (lane >> 4);
#pragma unroll
            for (int i = 0; i < 4; ++i) {
                const int mr = wm * 64 + i * 16 + (lane & 15);
                af[i] = *(const short8v*)(sA + mr * 128 + ((cc ^ (mr & 7)) << 4));
                const int nr = wn * 64 + i * 16 + (lane & 15);
                bfr[i] = *(const short8v*)(sB + nr * 128 + ((cc ^ (nr & 7)) << 4));
            }
#pragma unroll
            for (int i = 0; i < 4; ++i)
#pragma unroll
                for (int j = 0; j < 4; ++j)
                    acc[i][j] = __builtin_amdgcn_mfma_f32_16x16x32_bf16(
                        af[i], bfr[j], acc[i][j], 0, 0, 0);
        }
        __syncthreads();
    }

    float* Cf = (float*)d.C;
    u16* Cb = (u16*)d.C;
#pragma unroll
    for (int i = 0; i < 4; ++i) {
        const int row = m0 + wm * 64 + i * 16 + (lane >> 4) * 4;
#pragma unroll
        for (int j = 0; j < 4; ++j) {
            const int col = n0 + wn * 64 + j * 16 + (lane & 15);
            if (col < d.N) {
#pragma unroll
                for (int r = 0; r < 4; ++r) {
                    const float v = acc[i][j][r];
                    const size_t idx = (size_t)(row + r) * d.ldc + col;
                    if (d.epi == 0)      Cf[idx] = v;
                    else if (d.epi == 1) Cb[idx] = f2b(tanhf(v));
                    else if (d.epi == 2) { float t = fmaxf(v, 0.f); Cb[idx] = f2b(t * t); }
                    else                 Cf[idx] = 1.f / (1.f + __expf(-v));
                }
            }
        }
    }
}

// ============================================================
// Fused 5-group LoRA-up GEMM (K=32, fp32 vector) + shift-mix epilogue -> bf16
// ============================================================
__global__ __launch_bounds__(256)
void k_gemm_mix5(const float* __restrict__ XX, const float* __restrict__ w2,
                 const float* __restrict__ xb, const float* __restrict__ Hb,
                 u16* __restrict__ AMX) {
    constexpr int BM = 64, BK = 16, K = LRq, LDX = 5 * LRq;
    __shared__ __align__(16) float sA[BK][BM + 4];
    __shared__ __align__(16) float sB[BK][BM + 4];
    int g = blockIdx.z;
    const float* A = XX + g * LRq;
    const float* W = w2 + g * LRq;
    const float* bias = xb + g * Dq;
    u16* C = AMX + (size_t)g * Mq * Dq;
    int m0 = blockIdx.x * BM, n0 = blockIdx.y * BM;
    int tid = threadIdx.x;
    int tx = tid & 15, ty = tid >> 4;
    int lr = tid >> 2, lc = (tid & 3) * 4;
    float acc[4][4] = {};

    for (int k0 = 0; k0 < K; k0 += BK) {
        float4 av = *(const float4*)(A + (size_t)(m0 + lr) * LDX + k0 + lc);
        float4 bv = *(const float4*)(W + (size_t)(n0 + lr) * LDX + k0 + lc);
        sA[lc + 0][lr] = av.x; sA[lc + 1][lr] = av.y;
        sA[lc + 2][lr] = av.z; sA[lc + 3][lr] = av.w;
        sB[lc + 0][lr] = bv.x; sB[lc + 1][lr] = bv.y;
        sB[lc + 2][lr] = bv.z; sB[lc + 3][lr] = bv.w;
        __syncthreads();
#pragma unroll
        for (int kk = 0; kk < BK; kk++) {
            float4 a4 = *(const float4*)&sA[kk][ty * 4];
            float4 b4 = *(const float4*)&sB[kk][tx * 4];
            acc[0][0] += a4.x * b4.x; acc[0][1] += a4.x * b4.y;
            acc[0][2] += a4.x * b4.z; acc[0][3] += a4.x * b4.w;
            acc[1][0] += a4.y * b4.x; acc[1][1] += a4.y * b4.y;
            acc[1][2] += a4.y * b4.z; acc[1][3] += a4.y * b4.w;
            acc[2][0] += a4.z * b4.x; acc[2][1] += a4.z * b4.y;
            acc[2][2] += a4.z * b4.z; acc[2][3] += a4.z * b4.w;
            acc[3][0] += a4.w * b4.x; acc[3][1] += a4.w * b4.y;
            acc[3][2] += a4.w * b4.z; acc[3][3] += a4.w * b4.w;
        }
        __syncthreads();
    }

#pragma unroll
    for (int i = 0; i < 4; i++) {
        int row = m0 + ty * 4 + i;
        int t = row % Tq;
#pragma unroll
        for (int j = 0; j < 4; j++) {
            int col = n0 + tx * 4 + j;
            size_t idx = (size_t)row * Dq + col;
            float val = acc[i][j] + bias[col];
            float hv = Hb[idx];
            float pv = t ? Hb[idx - Dq] : 0.f;
            C[idx] = f2b(hv + (pv - hv) * val);
        }
    }
}

// ============================================================
// Chunked matmul scan (L=32).
// ============================================================
__global__ __launch_bounds__(256)
void k_prep_m(const float* __restrict__ Rp, const float* __restrict__ Kp,
              const float* __restrict__ Dp, const float* __restrict__ Vp,
              const float* __restrict__ bonus,
              float* __restrict__ RQd, float* __restrict__ KQg,
              float* __restrict__ DIAG, float* __restrict__ PC,
              float* __restrict__ MC) {
    int c = blockIdx.x, bh = blockIdx.y;
    int b = bh >> 2, h = bh & 3;
    __shared__ float Rl[CL2][68], Kl[CL2][68], Dl[CL2][68];
    __shared__ float Vl[CL2][128];
    __shared__ float Pl[64];
    int tid = threadIdx.x;
#pragma unroll
    for (int i = 0; i < 8; i++) {
        int idx = i * 256 + tid;
        int t = idx >> 6, k = idx & 63;
        size_t g = ((size_t)(b * Tq + c * CL2 + t) * Hq + h) * DKq + k;
        Rl[t][k] = Rp[g]; Kl[t][k] = Kp[g]; Dl[t][k] = Dp[g];
    }
#pragma unroll
    for (int i = 0; i < 16; i++) {
        int idx = i * 256 + tid;
        int t = idx >> 7, v = idx & 127;
        Vl[t][v] = Vp[((size_t)(b * Tq + c * CL2 + t) * Hq + h) * DVq + v];
    }
    __syncthreads();
    // DIAG (uses original r,k — before prefix overwrites)
    {
        int t = tid >> 3, kg = tid & 7;
        float p = 0.f;
#pragma unroll
        for (int i = 0; i < 8; i++) {
            int k = kg * 8 + i;
            p += Rl[t][k] * Kl[t][k] * bonus[h * DKq + k];
        }
        p += __shfl_down(p, 4, 8);
        p += __shfl_down(p, 2, 8);
        p += __shfl_down(p, 1, 8);
        if (kg == 0) DIAG[(size_t)bh * Tq + c * CL2 + t] = p;
    }
    __syncthreads();
    // per-channel serial prefix products
    if (tid < 64) {
        int k = tid;
        float p = 1.f;
        for (int t = 0; t < CL2; t++) {
            float d = Dl[t][k];
            Rl[t][k] *= p;       // r * Dprev
            p *= d;
            Kl[t][k] /= p;       // k / Dc
        }
        Pl[k] = p;
    }
    __syncthreads();
#pragma unroll
    for (int i = 0; i < 8; i++) {
        int idx = i * 256 + tid;
        int t = idx >> 6, k = idx & 63;
        size_t g = ((size_t)bh * Tq + c * CL2 + t) * DKq + k;
        RQd[g] = Rl[t][k];
        KQg[g] = Kl[t][k];
    }
    if (tid < 64) PC[(size_t)(bh * NC2 + c) * DKq + tid] = Pl[tid];
    // M = P (x) (KQ^T @ V)
    {
        int tk = tid >> 5, tv = tid & 31;
        float acc[8][4] = {};
        for (int t = 0; t < CL2; t++) {
            float4 ka = *(const float4*)&Kl[t][tk * 8];
            float4 kb = *(const float4*)&Kl[t][tk * 8 + 4];
            float4 v4 = *(const float4*)&Vl[t][tv * 4];
            float kv[8] = {ka.x, ka.y, ka.z, ka.w, kb.x, kb.y, kb.z, kb.w};
#pragma unroll
            for (int i = 0; i < 8; i++) {
                acc[i][0] = fmaf(kv[i], v4.x, acc[i][0]);
                acc[i][1] = fmaf(kv[i], v4.y, acc[i][1]);
                acc[i][2] = fmaf(kv[i], v4.z, acc[i][2]);
                acc[i][3] = fmaf(kv[i], v4.w, acc[i][3]);
            }
        }
#pragma unroll
        for (int i = 0; i < 8; i++) {
            int k = tk * 8 + i;
            float P = Pl[k];
            *(float4*)&MC[((size_t)(bh * NC2 + c) * DKq + k) * DVq + tv * 4] =
                make_float4(acc[i][0] * P, acc[i][1] * P, acc[i][2] * P, acc[i][3] * P);
        }
    }
}

// cross-chunk combine, in place
__global__ __launch_bounds__(256)
void k_combine2(float* __restrict__ S0MC, const float* __restrict__ PC) {
    int idx = blockIdx.x * 256 + threadIdx.x;
    int v = idx & 127;
    int k = (idx >> 7) & 63;
    int bh = idx >> 13;
    float s = 0.f;
    for (int c = 0; c < NC2; c++) {
        size_t p = (size_t)(bh * NC2 + c) * DKq + k;
        size_t m = p * DVq + v;
        float mc = S0MC[m];
        S0MC[m] = s;
        s = fmaf(PC[p], s, mc);
    }
}

// intra-chunk output + FUSED per-head groupnorm + swish gate -> bf16
__global__ __launch_bounds__(256)
void k_scan_o(const float* __restrict__ RQd, const float* __restrict__ KQg,
              const float* __restrict__ Vp, const float* __restrict__ S0,
              const float* __restrict__ DIAG, const float* __restrict__ Gp,
              const float* __restrict__ gng, const float* __restrict__ gnb,
              u16* __restrict__ OB) {
    int c = blockIdx.x, bh = blockIdx.y;
    int b = bh >> 2, h = bh & 3;
    __shared__ float RQl[CL2][68];
    __shared__ float KQt[DKq][36];     // transposed: KQt[k][s]
    __shared__ float Vl[CL2][128];
    __shared__ float S0l[DKq][128];
    __shared__ float Al[CL2][33];
    int tid = threadIdx.x;
#pragma unroll
    for (int i = 0; i < 8; i++) {
        int idx = i * 256 + tid;
        int t = idx >> 6, k = idx & 63;
        size_t g = ((size_t)bh * Tq + c * CL2 + t) * DKq + k;
        RQl[t][k] = RQd[g];
        KQt[k][t] = KQg[g];
    }
#pragma unroll
    for (int i = 0; i < 16; i++) {
        int idx = i * 256 + tid;
        int t = idx >> 7, v = idx & 127;
        Vl[t][v] = Vp[((size_t)(b * Tq + c * CL2 + t) * Hq + h) * DVq + v];
    }
#pragma unroll
    for (int i = 0; i < 32; i++) {
        int idx = i * 256 + tid;
        int k = idx >> 7, v = idx & 127;
        S0l[k][v] = S0[((size_t)(bh * NC2 + c) * DKq + k) * DVq + v];
    }
    __syncthreads();
    // A stage
    {
        int t = tid >> 3, sq = tid & 7;
        float a[4] = {};
        for (int k = 0; k < DKq; k++) {
            float rq = RQl[t][k];
            float4 k4 = *(const float4*)&KQt[k][sq * 4];
            a[0] = fmaf(rq, k4.x, a[0]);
            a[1] = fmaf(rq, k4.y, a[1]);
            a[2] = fmaf(rq, k4.z, a[2]);
            a[3] = fmaf(rq, k4.w, a[3]);
        }
        float diag = DIAG[(size_t)bh * Tq + c * CL2 + t];
#pragma unroll
        for (int j = 0; j < 4; j++) {
            int s = sq * 4 + j;
            Al[t][s] = (s < t) ? a[j] : (s == t ? diag : 0.f);
        }
    }
    __syncthreads();
    // O stage + groupnorm + gate
    {
        int t = tid >> 3, vg = tid & 7;
        float o[16] = {};
        for (int s = 0; s <= t; s++) {
            float a = Al[t][s];
#pragma unroll
            for (int q = 0; q < 4; q++) {
                float4 v4 = *(const float4*)&Vl[s][vg * 4 + q * 32];
                o[q * 4 + 0] = fmaf(a, v4.x, o[q * 4 + 0]);
                o[q * 4 + 1] = fmaf(a, v4.y, o[q * 4 + 1]);
                o[q * 4 + 2] = fmaf(a, v4.z, o[q * 4 + 2]);
                o[q * 4 + 3] = fmaf(a, v4.w, o[q * 4 + 3]);
            }
        }
        for (int k = 0; k < DKq; k++) {
            float rq = RQl[t][k];
#pragma unroll
            for (int q = 0; q < 4; q++) {
                float4 s4 = *(const float4*)&S0l[k][vg * 4 + q * 32];
                o[q * 4 + 0] = fmaf(rq, s4.x, o[q * 4 + 0]);
                o[q * 4 + 1] = fmaf(rq, s4.y, o[q * 4 + 1]);
                o[q * 4 + 2] = fmaf(rq, s4.z, o[q * 4 + 2]);
                o[q * 4 + 3] = fmaf(rq, s4.w, o[q * 4 + 3]);
            }
        }
        // groupnorm over the 128-wide row (spread across 8 lanes x 16 regs)
        float s = 0.f, q = 0.f;
#pragma unroll
        for (int i = 0; i < 16; i++) { s += o[i]; q += o[i] * o[i]; }
#pragma unroll
        for (int off = 4; off; off >>= 1) { s += __shfl_xor(s, off); q += __shfl_xor(q, off); }
        float mean = s * (1.f / DVq);
        float inv = rsqrtf(q * (1.f / DVq) - mean * mean + EPSq);
        size_t gb = ((size_t)(b * Tq + c * CL2 + t) * Hq + h) * DVq;
#pragma unroll
        for (int qd = 0; qd < 4; qd++) {
            int v0i = vg * 4 + qd * 32;
            float4 g4 = *(const float4*)&Gp[gb + v0i];
            ushort4 ob;
            float lnv, gv;
            gv = g4.x; lnv = (o[qd * 4 + 0] - mean) * inv * gng[v0i + 0] + gnb[v0i + 0];
            ob.x = f2b(lnv * (gv / (1.f + __expf(-gv))));
            gv = g4.y; lnv = (o[qd * 4 + 1] - mean) * inv * gng[v0i + 1] + gnb[v0i + 1];
            ob.y = f2b(lnv * (gv / (1.f + __expf(-gv))));
            gv = g4.z; lnv = (o[qd * 4 + 2] - mean) * inv * gng[v0i + 2] + gnb[v0i + 2];
            ob.z = f2b(lnv * (gv / (1.f + __expf(-gv))));
            gv = g4.w; lnv = (o[qd * 4 + 3] - mean) * inv * gng[v0i + 3] + gnb[v0i + 3];
            ob.w = f2b(lnv * (gv / (1.f + __expf(-gv))));
            *(ushort4*)&OB[gb + v0i] = ob;
        }
    }
}

// ============================================================
// Host-side launch
// ============================================================
extern "C" void kernel_launch(void* const* d_in, const int* in_sizes, int n_in,
                              void* d_out, int out_size, void* d_ws, size_t ws_size,
                              hipStream_t stream) {
    const float* x     = (const float*)d_in[0];
    const float* ln0_g = (const float*)d_in[1];
    const float* ln0_b = (const float*)d_in[2];
    const float* ln1_g = (const float*)d_in[3];
    const float* ln1_b = (const float*)d_in[4];
    const float* ln2_g = (const float*)d_in[5];
    const float* ln2_b = (const float*)d_in[6];
    const float* xp_mu = (const float*)d_in[7];
    const float* xp_w1 = (const float*)d_in[8];   // (160,512)
    const float* xp_w2 = (const float*)d_in[9];   // (512,160)
    const float* x_bias= (const float*)d_in[10];  // (5,512)
    const float* r_w   = (const float*)d_in[11];  // (256,512)
    const float* w_A   = (const float*)d_in[12];  // (64,512)
    const float* w_B   = (const float*)d_in[13];  // (256,64)
    const float* w_b   = (const float*)d_in[14];  // (256)
    const float* k_w   = (const float*)d_in[15];  // (256,512)
    const float* v_w   = (const float*)d_in[16];  // (512,512)
    const float* g_w   = (const float*)d_in[17];  // (512,512)
    const float* bonus = (const float*)d_in[18];  // (4,64)
    const float* gn_g  = (const float*)d_in[19];  // (128)
    const float* gn_b  = (const float*)d_in[20];
    const float* o_w   = (const float*)d_in[21];  // (512,512)
    const float* fk_mu = (const float*)d_in[22];
    const float* fk_w  = (const float*)d_in[23];  // (1024,512)
    const float* fr_mu = (const float*)d_in[24];
    const float* fr_w  = (const float*)d_in[25];  // (512,512)
    const float* fv_w  = (const float*)d_in[26];  // (512,1024)
    float* out = (float*)d_out;
    (void)in_sizes; (void)n_in; (void)out_size; (void)ws_size;

    const size_t MD = (size_t)Mq * Dq;  // 4M elems
    float* ws = (float*)d_ws;
    size_t off = 0;
    auto af32 = [&](size_t n) { float* p = ws + off; off += n; return p; };

    float* R    = af32(MD);                 // ln0 out (residual), live to o-GEMM
    float* Hb   = af32(MD);                 // ln1 out, live to mix5
    float* XX   = af32((size_t)Mq * 160);   // lora-down (fp32, mix5 A operand)
    float* Rproj= af32((size_t)Mq * 256);
    float* DEC  = af32((size_t)Mq * 256);
    float* KB   = af32((size_t)Mq * 256);
    float* VB   = af32(MD);
    float* GB   = af32(MD);
    float* PC   = af32((size_t)BH2 * NC2 * DKq);         // 64K
    float* S0MC = af32((size_t)BH2 * NC2 * DKq * DVq);   // 8.39M (M_c then S0, in place)
    float* DIAG = af32((size_t)BH2 * Tq);                // 32K

    u16* us = (u16*)(ws + off);
    size_t uo = 0;
    auto au16 = [&](size_t n) { u16* p = us + uo; uo += n; return p; };
    u16* MX0b = au16(MD);          // mix(h,xp_mu) bf16
    u16* AMXb = au16(5 * MD);      // 5 mixed GEMM inputs bf16
    u16* TAb  = au16((size_t)Mq * 64);
    u16* OBb  = au16(MD);          // gatenorm out bf16
    u16* wb_xp1 = au16(256 * 512); // padded 160->256 rows
    u16* wb_r   = au16(256 * 512);
    u16* wb_wA  = au16(128 * 512); // padded 64->128 rows
    u16* wb_wB  = au16(256 * 64);
    u16* wb_k   = au16(256 * 512);
    u16* wb_v   = au16(512 * 512);
    u16* wb_g   = au16(512 * 512);
    u16* wb_o   = au16(512 * 512);
    u16* wb_fk  = au16(1024 * 512);
    u16* wb_fr  = au16(512 * 512);
    u16* wb_fv  = au16(512 * 1024);

    // lifetime-checked aliases (stream-ordered, all disjoint in time):
    float* RQd = (float*)MX0b;            // MX0b dead after xp1-GEMM
    float* KQg = (float*)(AMXb + 4 * MD); // slice 4 dead after proj batch
    float* Z   = GB;                       // a+residual (GB dead after scan_o)
    float* RRb = VB;                       // sigmoid gate (VB dead after scan_o)
    u16* MXKb = AMXb;                      // slice 0 (dead after proj batch)
    u16* MXRb = AMXb + MD;                 // slice 1 (dead after proj batch)
    u16* KKb  = AMXb + 2 * MD;             // slices 2+3 (dead after proj batch)

    // 0) weights -> bf16
    WConv wc;
    const float* wsrc[11] = {xp_w1, r_w, w_A, w_B, k_w, v_w, g_w, o_w, fk_w, fr_w, fv_w};
    u16* wdst[11] = {wb_xp1, wb_r, wb_wA, wb_wB, wb_k, wb_v, wb_g, wb_o, wb_fk, wb_fr, wb_fv};
    int wn_[11]  = {160*512, 256*512, 64*512, 256*64, 256*512, 512*512, 512*512,
                    512*512, 1024*512, 512*512, 512*1024};
    int wnp[11]  = {256*512, 256*512, 128*512, 256*64, 256*512, 512*512, 512*512,
                    512*512, 1024*512, 512*512, 512*1024};
    for (int i = 0; i < 11; i++) { wc.src[i] = wsrc[i]; wc.dst[i] = wdst[i];
                                   wc.n[i] = wn_[i]; wc.npad[i] = wnp[i]; }
    k_wconv<<<dim3(64, 11), 256, 0, stream>>>(wc);

    // 1) pre-norms
    k_ln01<<<Mq, 256, 0, stream>>>(x, ln0_g, ln0_b, ln1_g, ln1_b, R, Hb);

    // 2) xx = tanh(mix(h, xp_mu) @ xp_w1^T)   [MFMA]
    k_mix1<<<Mq, 256, 0, stream>>>(Hb, xp_mu, MX0b);
    k_mgemm<ME_TANH_F32><<<dim3(64, 2), 256, 0, stream>>>(
        MX0b, 512, wb_xp1, 512, XX, 160, 160, 512, nullptr, nullptr, nullptr);

    // 3) mods + the 5 mixed GEMM inputs (K=32, vector fp32, bf16 out)
    k_gemm_mix5<<<dim3(128, 8, 5), 256, 0, stream>>>(XX, xp_w2, x_bias, Hb, AMXb);

    // 4) projections: ONE batched launch {r, wA, k, v, g}  [MFMA, 13 N-tiles]
    {
        MultiDesc md;
        md.g[0] = {AMXb + 0 * MD, wb_r,  (void*)Rproj, 512, 512, 256, 256, 512, 0};
        md.g[1] = {AMXb + 1 * MD, wb_wA, (void*)TAb,   512, 512,  64,  64, 512, 1};
        md.g[2] = {AMXb + 2 * MD, wb_k,  (void*)KB,    512, 512, 256, 256, 512, 0};
        md.g[3] = {AMXb + 3 * MD, wb_v,  (void*)VB,    512, 512, 512, 512, 512, 0};
        md.g[4] = {AMXb + 4 * MD, wb_g,  (void*)GB,    512, 512, 512, 512, 512, 0};
        int gid[16]   = {0,0, 1, 2,2, 3,3,3,3, 4,4,4,4, 0,0,0};
        int ntile[16] = {0,1, 0, 0,1, 0,1,2,3, 0,1,2,3, 0,0,0};
        for (int i = 0; i < 16; i++) { md.gid[i] = gid[i]; md.ntile[i] = ntile[i]; }
        k_mgemm_multi<<<dim3(64, 13), 256, 0, stream>>>(md);
    }
    // wB depends on TAb
    k_mgemm<ME_DECAY><<<dim3(64, 2), 256, 0, stream>>>(
        TAb, 64, wb_wB, 64, DEC, 256, 256, 64, w_b, nullptr, nullptr);

    // 5) chunked matmul scan (+ fused gatenorm/gate in scan_o)
    k_prep_m<<<dim3(NC2, BH2), 256, 0, stream>>>(Rproj, KB, DEC, VB, bonus,
                                                 RQd, KQg, DIAG, PC, S0MC);
    k_combine2<<<(BH2 * DKq * DVq) / 256, 256, 0, stream>>>(S0MC, PC);
    k_scan_o<<<dim3(NC2, BH2), 256, 0, stream>>>(RQd, KQg, VB, S0MC, DIAG,
                                                 GB, gn_g, gn_b, OBb);

    // 6) output proj + residual [MFMA]
    k_mgemm<ME_RESID><<<dim3(64, 4), 256, 0, stream>>>(
        OBb, 512, wb_o, 512, Z, 512, 512, 512, nullptr, R, nullptr);

    // 7) channel-mix FFN: fused ln2+mix, then batched {fk, fr}, then fv [MFMA]
    k_ln2mix<<<Mq, 256, 0, stream>>>(Z, ln2_g, ln2_b, fk_mu, fr_mu, MXKb, MXRb);
    {
        MultiDesc md;
        md.g[0] = {MXKb, wb_fk, (void*)KKb, 512, 512, 1024, 1024, 512, 2};
        md.g[1] = {MXRb, wb_fr, (void*)RRb, 512, 512,  512,  512, 512, 3};
        int gid[16]   = {0,0,0,0,0,0,0,0, 1,1,1,1, 0,0,0,0};
        int ntile[16] = {0,1,2,3,4,5,6,7, 0,1,2,3, 0,0,0,0};
        for (int i = 0; i < 16; i++) { md.gid[i] = gid[i]; md.ntile[i] = ntile[i]; }
        k_mgemm_multi<<<dim3(64, 12), 256, 0, stream>>>(md);
    }
    k_mgemm<ME_GATED><<<dim3(64, 4), 256, 0, stream>>>(
        KKb, 1024, wb_fv, 1024, out, 512, 512, 1024, nullptr, Z, RRb);
}

// Round 11
// 408.814 us; speedup vs baseline: 1.5082x; 1.0581x over previous
//
#include <hip/hip_runtime.h>
#include <math.h>

// ---- problem constants (from reference) ----
constexpr int Bq = 4, Tq = 2048, Dq = 512, Hq = 4, DKq = 64, DVq = 128, LRq = 32;
constexpr int Mq = Bq * Tq;           // 8192 rows
constexpr float EPSq = 1e-5f;
// chunked scan: L=32 keeps decay dynamic range within fp32 (worst ~e^46)
constexpr int CL2 = 32, NC2 = Tq / CL2, BH2 = Bq * Hq;

typedef unsigned short u16;
typedef __attribute__((ext_vector_type(8))) short short8v;  // 8 bf16 (4 VGPR)
typedef __attribute__((ext_vector_type(4))) float f32x4;

// float -> bf16 (round-to-nearest-even)
__device__ __forceinline__ u16 f2b(float f) {
    unsigned u = __float_as_uint(f);
    u += 0x7fffu + ((u >> 16) & 1);
    return (u16)(u >> 16);
}

// async global->LDS, 16B per lane (dest = uniform base + lane*16)
__device__ __forceinline__ void gl_lds16(const void* g, void* l) {
    __builtin_amdgcn_global_load_lds(
        (const __attribute__((address_space(1))) unsigned int*)g,
        (__attribute__((address_space(3))) unsigned int*)l, 16, 0, 0);
}

// ============================================================
// LayerNorm kernels (fp32)
// ============================================================
__global__ __launch_bounds__(256)
void k_ln01(const float* __restrict__ x,
            const float* __restrict__ g0, const float* __restrict__ b0,
            const float* __restrict__ g1, const float* __restrict__ b1,
            float* __restrict__ Rout, float* __restrict__ Hout) {
    __shared__ float red[8];
    int row = blockIdx.x, tid = threadIdx.x;
    const float* xr = x + (size_t)row * Dq;
    float v0 = xr[tid], v1 = xr[tid + 256];

    float s = v0 + v1, q = v0 * v0 + v1 * v1;
#pragma unroll
    for (int o = 32; o; o >>= 1) { s += __shfl_down(s, o); q += __shfl_down(q, o); }
    if ((tid & 63) == 0) { red[tid >> 6] = s; red[4 + (tid >> 6)] = q; }
    __syncthreads();
    s = red[0] + red[1] + red[2] + red[3];
    q = red[4] + red[5] + red[6] + red[7];
    float mean = s * (1.f / Dq);
    float inv = rsqrtf(q * (1.f / Dq) - mean * mean + EPSq);
    float r0 = (v0 - mean) * inv * g0[tid] + b0[tid];
    float r1 = (v1 - mean) * inv * g0[tid + 256] + b0[tid + 256];
    Rout[(size_t)row * Dq + tid] = r0;
    Rout[(size_t)row * Dq + tid + 256] = r1;

    s = r0 + r1; q = r0 * r0 + r1 * r1;
#pragma unroll
    for (int o = 32; o; o >>= 1) { s += __shfl_down(s, o); q += __shfl_down(q, o); }
    __syncthreads();
    if ((tid & 63) == 0) { red[tid >> 6] = s; red[4 + (tid >> 6)] = q; }
    __syncthreads();
    s = red[0] + red[1] + red[2] + red[3];
    q = red[4] + red[5] + red[6] + red[7];
    mean = s * (1.f / Dq);
    inv = rsqrtf(q * (1.f / Dq) - mean * mean + EPSq);
    Hout[(size_t)row * Dq + tid] = (r0 - mean) * inv * g1[tid] + b1[tid];
    Hout[(size_t)row * Dq + tid + 256] = (r1 - mean) * inv * g1[tid + 256] + b1[tid + 256];
}

// token-shift mix with constant mu vector: out = h + (shift(h)-h)*mu  -> bf16
__global__ __launch_bounds__(256)
void k_mix1(const float* __restrict__ h, const float* __restrict__ mu,
            u16* __restrict__ out) {
    int row = blockIdx.x, t = row % Tq;
    const float* hr = h + (size_t)row * Dq;
#pragma unroll
    for (int it = 0; it < 2; it++) {
        int d = threadIdx.x + it * 256;
        float hv = hr[d];
        float pv = t ? hr[d - Dq] : 0.f;
        out[(size_t)row * Dq + d] = f2b(hv + (pv - hv) * mu[d]);
    }
}

// fused ln2 + token-shift mix (recomputes row-1's LN; eliminates H2 buffer)
__global__ __launch_bounds__(256)
void k_ln2mix(const float* __restrict__ Z,
              const float* __restrict__ g2, const float* __restrict__ b2,
              const float* __restrict__ muK, const float* __restrict__ muR,
              u16* __restrict__ outK, u16* __restrict__ outR) {
    __shared__ float red[16];
    int row = blockIdx.x, t = row % Tq, tid = threadIdx.x;
    const float* zr = Z + (size_t)row * Dq;
    float c0 = zr[tid], c1 = zr[tid + 256];
    float p0 = 0.f, p1 = 0.f;
    if (t) { p0 = zr[tid - Dq]; p1 = zr[tid + 256 - Dq]; }
    float sc = c0 + c1, qc = c0 * c0 + c1 * c1;
    float sp = p0 + p1, qp = p0 * p0 + p1 * p1;
#pragma unroll
    for (int o = 32; o; o >>= 1) {
        sc += __shfl_down(sc, o); qc += __shfl_down(qc, o);
        sp += __shfl_down(sp, o); qp += __shfl_down(qp, o);
    }
    if ((tid & 63) == 0) {
        int w = tid >> 6;
        red[w] = sc; red[4 + w] = qc; red[8 + w] = sp; red[12 + w] = qp;
    }
    __syncthreads();
    sc = red[0] + red[1] + red[2] + red[3];
    qc = red[4] + red[5] + red[6] + red[7];
    sp = red[8] + red[9] + red[10] + red[11];
    qp = red[12] + red[13] + red[14] + red[15];
    float mc = sc * (1.f / Dq), ic = rsqrtf(qc * (1.f / Dq) - mc * mc + EPSq);
    float mp = sp * (1.f / Dq), ip = rsqrtf(qp * (1.f / Dq) - mp * mp + EPSq);
#pragma unroll
    for (int it = 0; it < 2; it++) {
        int d = tid + it * 256;
        float cv = it ? c1 : c0, pv = it ? p1 : p0;
        float hc = (cv - mc) * ic * g2[d] + b2[d];
        float hp = t ? ((pv - mp) * ip * g2[d] + b2[d]) : 0.f;
        float dl = hp - hc;
        outK[(size_t)row * Dq + d] = f2b(hc + dl * muK[d]);
        outR[(size_t)row * Dq + d] = f2b(hc + dl * muR[d]);
    }
}

// weight fp32 -> bf16 conversion (padded rows zeroed)
struct WConv {
    const float* src[11];
    u16* dst[11];
    int n[11];
    int npad[11];
};
__global__ __launch_bounds__(256)
void k_wconv(WConv wc) {
    int w = blockIdx.y;
    const float* s = wc.src[w];
    u16* d = wc.dst[w];
    int n = wc.n[w], np = wc.npad[w];
    for (int i = blockIdx.x * 256 + threadIdx.x; i < np; i += gridDim.x * 256)
        d[i] = (i < n) ? f2b(s[i]) : (u16)0;
}

// ============================================================
// bf16 MFMA GEMM core: 128x128 tile, BK=64, 4 waves (2x2),
// 4x4 16x16x32 frags/wave, global_load_lds staging, XOR-swizzled LDS.
// 2-PHASE double-buffered pipeline: STAGE(next) issued before compute(cur),
// raw s_barrier (no __syncthreads auto-drain), one vmcnt(0)+barrier per iter.
// ============================================================
enum MEpi { ME_NONE, ME_TANH_F32, ME_TANH_B16, ME_DECAY, ME_RESID,
            ME_RELUSQ_B16, ME_SIGMOID, ME_GATED };

template <int EPI>
__global__ __launch_bounds__(256)
void k_mgemm(const u16* __restrict__ A, int lda,
             const u16* __restrict__ W, int ldw,
             void* __restrict__ Cout, int ldc,
             int N, int K,
             const float* __restrict__ bias,   // DECAY: w_b
             const float* __restrict__ P1,     // RESID: residual ; GATED: z
             const float* __restrict__ P2) {   // GATED: rr
    __shared__ __align__(16) char smem[65536];   // 2 × (sA 16KB | sB 16KB)
    const int m0 = blockIdx.x * 128, n0 = blockIdx.y * 128;
    const int tid = threadIdx.x, lane = tid & 63, wid = tid >> 6;
    const int wm = wid >> 1, wn = wid & 1;     // 2x2 wave grid, 64x64 each

    f32x4 acc[4][4] = {};

    const int rl = lane >> 3;
    const int ccs = (lane & 7) ^ rl;
    const u16* ga = A + (size_t)(m0 + wid * 32 + rl) * lda + ccs * 8;
    const u16* gb = W + (size_t)(n0 + wid * 32 + rl) * ldw + ccs * 8;
    const int lofs = (wid * 32) * 128;

    auto STAGE = [&](int buf, int kt) {
        char* la = smem + buf * 32768 + lofs;
        char* lb = smem + buf * 32768 + 16384 + lofs;
        const int k0 = kt << 6;
#pragma unroll
        for (int i = 0; i < 4; ++i) {
            gl_lds16(ga + (size_t)(i * 8) * lda + k0, la + i * 8 * 128);
            gl_lds16(gb + (size_t)(i * 8) * ldw + k0, lb + i * 8 * 128);
        }
    };

    const int nkt = K >> 6;
    STAGE(0, 0);
    asm volatile("s_waitcnt vmcnt(0)" ::: "memory");
    __builtin_amdgcn_s_barrier();

    int cur = 0;
    for (int kt = 0; kt < nkt; ++kt) {
        if (kt + 1 < nkt) STAGE(cur ^ 1, kt + 1);   // prefetch next K-tile
        const char* sA = smem + cur * 32768;
        const char* sB = sA + 16384;
        __builtin_amdgcn_s_setprio(1);
#pragma unroll
        for (int ks = 0; ks < 2; ++ks) {
            short8v af[4], bfr[4];
            const int cc = ks * 4 + (lane >> 4);
#pragma unroll
            for (int i = 0; i < 4; ++i) {
                const int mr = wm * 64 + i * 16 + (lane & 15);
                af[i] = *(const short8v*)(sA + mr * 128 + ((cc ^ (mr & 7)) << 4));
                const int nr = wn * 64 + i * 16 + (lane & 15);
                bfr[i] = *(const short8v*)(sB + nr * 128 + ((cc ^ (nr & 7)) << 4));
            }
#pragma unroll
            for (int i = 0; i < 4; ++i)
#pragma unroll
                for (int j = 0; j < 4; ++j)
                    acc[i][j] = __builtin_amdgcn_mfma_f32_16x16x32_bf16(
                        af[i], bfr[j], acc[i][j], 0, 0, 0);
        }
        __builtin_amdgcn_s_setprio(0);
        asm volatile("s_waitcnt vmcnt(0)" ::: "memory");
        __builtin_amdgcn_s_barrier();
        cur ^= 1;
    }

    float* Cf = (float*)Cout;
    u16* Cb = (u16*)Cout;
#pragma unroll
    for (int i = 0; i < 4; ++i) {
        const int row = m0 + wm * 64 + i * 16 + (lane >> 4) * 4;
#pragma unroll
        for (int j = 0; j < 4; ++j) {
            const int col = n0 + wn * 64 + j * 16 + (lane & 15);
            if (col < N) {
#pragma unroll
                for (int r = 0; r < 4; ++r) {
                    const float v = acc[i][j][r];
                    const size_t idx = (size_t)(row + r) * ldc + col;
                    if constexpr (EPI == ME_NONE)        Cf[idx] = v;
                    else if constexpr (EPI == ME_TANH_F32) Cf[idx] = tanhf(v);
                    else if constexpr (EPI == ME_TANH_B16) Cb[idx] = f2b(tanhf(v));
                    else if constexpr (EPI == ME_DECAY)  Cf[idx] = expf(-expf(v + bias[col]));
                    else if constexpr (EPI == ME_RESID)  Cf[idx] = v + P1[idx];
                    else if constexpr (EPI == ME_RELUSQ_B16) {
                        float t = fmaxf(v, 0.f); Cb[idx] = f2b(t * t);
                    }
                    else if constexpr (EPI == ME_SIGMOID) Cf[idx] = 1.f / (1.f + __expf(-v));
                    else                                  Cf[idx] = P1[idx] + P2[idx] * v;
                }
            }
        }
    }
}

// ---- batched heterogeneous MFMA GEMM: one launch, many sub-GEMMs ----
struct GemmDesc {
    const u16* A; const u16* W; void* C;
    int lda, ldw, ldc, N, K, epi;   // epi: 0 NONE(f32) 1 TANH_B16 2 RELUSQ_B16 3 SIGMOID(f32)
};
struct MultiDesc {
    GemmDesc g[5];
    int gid[16];     // blockIdx.y -> gemm id
    int ntile[16];   // blockIdx.y -> n-tile within gemm
};

__global__ __launch_bounds__(256)
void k_mgemm_multi(MultiDesc md) {
    __shared__ __align__(16) char smem[65536];
    const GemmDesc d = md.g[md.gid[blockIdx.y]];
    const int m0 = blockIdx.x * 128, n0 = md.ntile[blockIdx.y] * 128;
    const int tid = threadIdx.x, lane = tid & 63, wid = tid >> 6;
    const int wm = wid >> 1, wn = wid & 1;

    f32x4 acc[4][4] = {};

    const int rl = lane >> 3;
    const int ccs = (lane & 7) ^ rl;
    const u16* ga = d.A + (size_t)(m0 + wid * 32 + rl) * d.lda + ccs * 8;
    const u16* gb = d.W + (size_t)(n0 + wid * 32 + rl) * d.ldw + ccs * 8;
    const int lofs = (wid * 32) * 128;

    auto STAGE = [&](int buf, int kt) {
        char* la = smem + buf * 32768 + lofs;
        char* lb = smem + buf * 32768 + 16384 + lofs;
        const int k0 = kt << 6;
#pragma unroll
        for (int i = 0; i < 4; ++i) {
            gl_lds16(ga + (size_t)(i * 8) * d.lda + k0, la + i * 8 * 128);
            gl_lds16(gb + (size_t)(i * 8) * d.ldw + k0, lb + i * 8 * 128);
        }
    };

    const int nkt = d.K >> 6;
    STAGE(0, 0);
    asm volatile("s_waitcnt vmcnt(0)" ::: "memory");
    __builtin_amdgcn_s_barrier();

    int cur = 0;
    for (int kt = 0; kt < nkt; ++kt) {
        if (kt + 1 < nkt) STAGE(cur ^ 1, kt + 1);
        const char* sA = smem + cur * 32768;
        const char* sB = sA + 16384;
        __builtin_amdgcn_s_setprio(1);
#pragma unroll
        for (int ks = 0; ks < 2; ++ks) {
            short8v af[4], bfr[4];
            const int cc = ks * 4 + (lane >> 4);
#pragma unroll
            for (int i = 0; i < 4; ++i) {
                const int mr = wm * 64 + i * 16 + (lane & 15);
                af[i] = *(const short8v*)(sA + mr * 128 + ((cc ^ (mr & 7)) << 4));
                const int nr = wn * 64 + i * 16 + (lane & 15);
                bfr[i] = *(const short8v*)(sB + nr * 128 + ((cc ^ (nr & 7)) << 4));
            }
#pragma unroll
            for (int i = 0; i < 4; ++i)
#pragma unroll
                for (int j = 0; j < 4; ++j)
                    acc[i][j] = __builtin_amdgcn_mfma_f32_16x16x32_bf16(
                        af[i], bfr[j], acc[i][j], 0, 0, 0);
        }
        __builtin_amdgcn_s_setprio(0);
        asm volatile("s_waitcnt vmcnt(0)" ::: "memory");
        __builtin_amdgcn_s_barrier();
        cur ^= 1;
    }

    float* Cf = (float*)d.C;
    u16* Cb = (u16*)d.C;
#pragma unroll
    for (int i = 0; i < 4; ++i) {
        const int row = m0 + wm * 64 + i * 16 + (lane >> 4) * 4;
#pragma unroll
        for (int j = 0; j < 4; ++j) {
            const int col = n0 + wn * 64 + j * 16 + (lane & 15);
            if (col < d.N) {
#pragma unroll
                for (int r = 0; r < 4; ++r) {
                    const float v = acc[i][j][r];
                    const size_t idx = (size_t)(row + r) * d.ldc + col;
                    if (d.epi == 0)      Cf[idx] = v;
                    else if (d.epi == 1) Cb[idx] = f2b(tanhf(v));
                    else if (d.epi == 2) { float t = fmaxf(v, 0.f); Cb[idx] = f2b(t * t); }
                    else                 Cf[idx] = 1.f / (1.f + __expf(-v));
                }
            }
        }
    }
}

// ============================================================
// Fused 5-group LoRA-up GEMM (K=32, fp32 vector) + shift-mix epilogue -> bf16
// ============================================================
__global__ __launch_bounds__(256)
void k_gemm_mix5(const float* __restrict__ XX, const float* __restrict__ w2,
                 const float* __restrict__ xb, const float* __restrict__ Hb,
                 u16* __restrict__ AMX) {
    constexpr int BM = 64, BK = 16, K = LRq, LDX = 5 * LRq;
    __shared__ __align__(16) float sA[BK][BM + 4];
    __shared__ __align__(16) float sB[BK][BM + 4];
    int g = blockIdx.z;
    const float* A = XX + g * LRq;
    const float* W = w2 + g * LRq;
    const float* bias = xb + g * Dq;
    u16* C = AMX + (size_t)g * Mq * Dq;
    int m0 = blockIdx.x * BM, n0 = blockIdx.y * BM;
    int tid = threadIdx.x;
    int tx = tid & 15, ty = tid >> 4;
    int lr = tid >> 2, lc = (tid & 3) * 4;
    float acc[4][4] = {};

    for (int k0 = 0; k0 < K; k0 += BK) {
        float4 av = *(const float4*)(A + (size_t)(m0 + lr) * LDX + k0 + lc);
        float4 bv = *(const float4*)(W + (size_t)(n0 + lr) * LDX + k0 + lc);
        sA[lc + 0][lr] = av.x; sA[lc + 1][lr] = av.y;
        sA[lc + 2][lr] = av.z; sA[lc + 3][lr] = av.w;
        sB[lc + 0][lr] = bv.x; sB[lc + 1][lr] = bv.y;
        sB[lc + 2][lr] = bv.z; sB[lc + 3][lr] = bv.w;
        __syncthreads();
#pragma unroll
        for (int kk = 0; kk < BK; kk++) {
            float4 a4 = *(const float4*)&sA[kk][ty * 4];
            float4 b4 = *(const float4*)&sB[kk][tx * 4];
            acc[0][0] += a4.x * b4.x; acc[0][1] += a4.x * b4.y;
            acc[0][2] += a4.x * b4.z; acc[0][3] += a4.x * b4.w;
            acc[1][0] += a4.y * b4.x; acc[1][1] += a4.y * b4.y;
            acc[1][2] += a4.y * b4.z; acc[1][3] += a4.y * b4.w;
            acc[2][0] += a4.z * b4.x; acc[2][1] += a4.z * b4.y;
            acc[2][2] += a4.z * b4.z; acc[2][3] += a4.z * b4.w;
            acc[3][0] += a4.w * b4.x; acc[3][1] += a4.w * b4.y;
            acc[3][2] += a4.w * b4.z; acc[3][3] += a4.w * b4.w;
        }
        __syncthreads();
    }

#pragma unroll
    for (int i = 0; i < 4; i++) {
        int row = m0 + ty * 4 + i;
        int t = row % Tq;
#pragma unroll
        for (int j = 0; j < 4; j++) {
            int col = n0 + tx * 4 + j;
            size_t idx = (size_t)row * Dq + col;
            float val = acc[i][j] + bias[col];
            float hv = Hb[idx];
            float pv = t ? Hb[idx - Dq] : 0.f;
            C[idx] = f2b(hv + (pv - hv) * val);
        }
    }
}

// ============================================================
// Chunked matmul scan (L=32).
// ============================================================
__global__ __launch_bounds__(256)
void k_prep_m(const float* __restrict__ Rp, const float* __restrict__ Kp,
              const float* __restrict__ Dp, const float* __restrict__ Vp,
              const float* __restrict__ bonus,
              float* __restrict__ RQd, float* __restrict__ KQg,
              float* __restrict__ DIAG, float* __restrict__ PC,
              float* __restrict__ MC) {
    int c = blockIdx.x, bh = blockIdx.y;
    int b = bh >> 2, h = bh & 3;
    __shared__ float Rl[CL2][68], Kl[CL2][68], Dl[CL2][68];
    __shared__ float Vl[CL2][128];
    __shared__ float Pl[64];
    int tid = threadIdx.x;
#pragma unroll
    for (int i = 0; i < 8; i++) {
        int idx = i * 256 + tid;
        int t = idx >> 6, k = idx & 63;
        size_t g = ((size_t)(b * Tq + c * CL2 + t) * Hq + h) * DKq + k;
        Rl[t][k] = Rp[g]; Kl[t][k] = Kp[g]; Dl[t][k] = Dp[g];
    }
#pragma unroll
    for (int i = 0; i < 16; i++) {
        int idx = i * 256 + tid;
        int t = idx >> 7, v = idx & 127;
        Vl[t][v] = Vp[((size_t)(b * Tq + c * CL2 + t) * Hq + h) * DVq + v];
    }
    __syncthreads();
    // DIAG (uses original r,k — before prefix overwrites)
    {
        int t = tid >> 3, kg = tid & 7;
        float p = 0.f;
#pragma unroll
        for (int i = 0; i < 8; i++) {
            int k = kg * 8 + i;
            p += Rl[t][k] * Kl[t][k] * bonus[h * DKq + k];
        }
        p += __shfl_down(p, 4, 8);
        p += __shfl_down(p, 2, 8);
        p += __shfl_down(p, 1, 8);
        if (kg == 0) DIAG[(size_t)bh * Tq + c * CL2 + t] = p;
    }
    __syncthreads();
    // per-channel serial prefix products
    if (tid < 64) {
        int k = tid;
        float p = 1.f;
        for (int t = 0; t < CL2; t++) {
            float d = Dl[t][k];
            Rl[t][k] *= p;       // r * Dprev
            p *= d;
            Kl[t][k] /= p;       // k / Dc
        }
        Pl[k] = p;
    }
    __syncthreads();
#pragma unroll
    for (int i = 0; i < 8; i++) {
        int idx = i * 256 + tid;
        int t = idx >> 6, k = idx & 63;
        size_t g = ((size_t)bh * Tq + c * CL2 + t) * DKq + k;
        RQd[g] = Rl[t][k];
        KQg[g] = Kl[t][k];
    }
    if (tid < 64) PC[(size_t)(bh * NC2 + c) * DKq + tid] = Pl[tid];
    // M = P (x) (KQ^T @ V)
    {
        int tk = tid >> 5, tv = tid & 31;
        float acc[8][4] = {};
        for (int t = 0; t < CL2; t++) {
            float4 ka = *(const float4*)&Kl[t][tk * 8];
            float4 kb = *(const float4*)&Kl[t][tk * 8 + 4];
            float4 v4 = *(const float4*)&Vl[t][tv * 4];
            float kv[8] = {ka.x, ka.y, ka.z, ka.w, kb.x, kb.y, kb.z, kb.w};
#pragma unroll
            for (int i = 0; i < 8; i++) {
                acc[i][0] = fmaf(kv[i], v4.x, acc[i][0]);
                acc[i][1] = fmaf(kv[i], v4.y, acc[i][1]);
                acc[i][2] = fmaf(kv[i], v4.z, acc[i][2]);
                acc[i][3] = fmaf(kv[i], v4.w, acc[i][3]);
            }
        }
#pragma unroll
        for (int i = 0; i < 8; i++) {
            int k = tk * 8 + i;
            float P = Pl[k];
            *(float4*)&MC[((size_t)(bh * NC2 + c) * DKq + k) * DVq + tv * 4] =
                make_float4(acc[i][0] * P, acc[i][1] * P, acc[i][2] * P, acc[i][3] * P);
        }
    }
}

// cross-chunk combine, in place
__global__ __launch_bounds__(256)
void k_combine2(float* __restrict__ S0MC, const float* __restrict__ PC) {
    int idx = blockIdx.x * 256 + threadIdx.x;
    int v = idx & 127;
    int k = (idx >> 7) & 63;
    int bh = idx >> 13;
    float s = 0.f;
    for (int c = 0; c < NC2; c++) {
        size_t p = (size_t)(bh * NC2 + c) * DKq + k;
        size_t m = p * DVq + v;
        float mc = S0MC[m];
        S0MC[m] = s;
        s = fmaf(PC[p], s, mc);
    }
}

// intra-chunk output + FUSED per-head groupnorm + swish gate -> bf16
__global__ __launch_bounds__(256)
void k_scan_o(const float* __restrict__ RQd, const float* __restrict__ KQg,
              const float* __restrict__ Vp, const float* __restrict__ S0,
              const float* __restrict__ DIAG, const float* __restrict__ Gp,
              const float* __restrict__ gng, const float* __restrict__ gnb,
              u16* __restrict__ OB) {
    int c = blockIdx.x, bh = blockIdx.y;
    int b = bh >> 2, h = bh & 3;
    __shared__ float RQl[CL2][68];
    __shared__ float KQt[DKq][36];     // transposed: KQt[k][s]
    __shared__ float Vl[CL2][128];
    __shared__ float S0l[DKq][128];
    __shared__ float Al[CL2][33];
    int tid = threadIdx.x;
#pragma unroll
    for (int i = 0; i < 8; i++) {
        int idx = i * 256 + tid;
        int t = idx >> 6, k = idx & 63;
        size_t g = ((size_t)bh * Tq + c * CL2 + t) * DKq + k;
        RQl[t][k] = RQd[g];
        KQt[k][t] = KQg[g];
    }
#pragma unroll
    for (int i = 0; i < 16; i++) {
        int idx = i * 256 + tid;
        int t = idx >> 7, v = idx & 127;
        Vl[t][v] = Vp[((size_t)(b * Tq + c * CL2 + t) * Hq + h) * DVq + v];
    }
#pragma unroll
    for (int i = 0; i < 32; i++) {
        int idx = i * 256 + tid;
        int k = idx >> 7, v = idx & 127;
        S0l[k][v] = S0[((size_t)(bh * NC2 + c) * DKq + k) * DVq + v];
    }
    __syncthreads();
    // A stage
    {
        int t = tid >> 3, sq = tid & 7;
        float a[4] = {};
        for (int k = 0; k < DKq; k++) {
            float rq = RQl[t][k];
            float4 k4 = *(const float4*)&KQt[k][sq * 4];
            a[0] = fmaf(rq, k4.x, a[0]);
            a[1] = fmaf(rq, k4.y, a[1]);
            a[2] = fmaf(rq, k4.z, a[2]);
            a[3] = fmaf(rq, k4.w, a[3]);
        }
        float diag = DIAG[(size_t)bh * Tq + c * CL2 + t];
#pragma unroll
        for (int j = 0; j < 4; j++) {
            int s = sq * 4 + j;
            Al[t][s] = (s < t) ? a[j] : (s == t ? diag : 0.f);
        }
    }
    __syncthreads();
    // O stage + groupnorm + gate
    {
        int t = tid >> 3, vg = tid & 7;
        float o[16] = {};
        for (int s = 0; s <= t; s++) {
            float a = Al[t][s];
#pragma unroll
            for (int q = 0; q < 4; q++) {
                float4 v4 = *(const float4*)&Vl[s][vg * 4 + q * 32];
                o[q * 4 + 0] = fmaf(a, v4.x, o[q * 4 + 0]);
                o[q * 4 + 1] = fmaf(a, v4.y, o[q * 4 + 1]);
                o[q * 4 + 2] = fmaf(a, v4.z, o[q * 4 + 2]);
                o[q * 4 + 3] = fmaf(a, v4.w, o[q * 4 + 3]);
            }
        }
        for (int k = 0; k < DKq; k++) {
            float rq = RQl[t][k];
#pragma unroll
            for (int q = 0; q < 4; q++) {
                float4 s4 = *(const float4*)&S0l[k][vg * 4 + q * 32];
                o[q * 4 + 0] = fmaf(rq, s4.x, o[q * 4 + 0]);
                o[q * 4 + 1] = fmaf(rq, s4.y, o[q * 4 + 1]);
                o[q * 4 + 2] = fmaf(rq, s4.z, o[q * 4 + 2]);
                o[q * 4 + 3] = fmaf(rq, s4.w, o[q * 4 + 3]);
            }
        }
        // groupnorm over the 128-wide row (spread across 8 lanes x 16 regs)
        float s = 0.f, q = 0.f;
#pragma unroll
        for (int i = 0; i < 16; i++) { s += o[i]; q += o[i] * o[i]; }
#pragma unroll
        for (int off = 4; off; off >>= 1) { s += __shfl_xor(s, off); q += __shfl_xor(q, off); }
        float mean = s * (1.f / DVq);
        float inv = rsqrtf(q * (1.f / DVq) - mean * mean + EPSq);
        size_t gb = ((size_t)(b * Tq + c * CL2 + t) * Hq + h) * DVq;
#pragma unroll
        for (int qd = 0; qd < 4; qd++) {
            int v0i = vg * 4 + qd * 32;
            float4 g4 = *(const float4*)&Gp[gb + v0i];
            ushort4 ob;
            float lnv, gv;
            gv = g4.x; lnv = (o[qd * 4 + 0] - mean) * inv * gng[v0i + 0] + gnb[v0i + 0];
            ob.x = f2b(lnv * (gv / (1.f + __expf(-gv))));
            gv = g4.y; lnv = (o[qd * 4 + 1] - mean) * inv * gng[v0i + 1] + gnb[v0i + 1];
            ob.y = f2b(lnv * (gv / (1.f + __expf(-gv))));
            gv = g4.z; lnv = (o[qd * 4 + 2] - mean) * inv * gng[v0i + 2] + gnb[v0i + 2];
            ob.z = f2b(lnv * (gv / (1.f + __expf(-gv))));
            gv = g4.w; lnv = (o[qd * 4 + 3] - mean) * inv * gng[v0i + 3] + gnb[v0i + 3];
            ob.w = f2b(lnv * (gv / (1.f + __expf(-gv))));
            *(ushort4*)&OB[gb + v0i] = ob;
        }
    }
}

// ============================================================
// Host-side launch
// ============================================================
extern "C" void kernel_launch(void* const* d_in, const int* in_sizes, int n_in,
                              void* d_out, int out_size, void* d_ws, size_t ws_size,
                              hipStream_t stream) {
    const float* x     = (const float*)d_in[0];
    const float* ln0_g = (const float*)d_in[1];
    const float* ln0_b = (const float*)d_in[2];
    const float* ln1_g = (const float*)d_in[3];
    const float* ln1_b = (const float*)d_in[4];
    const float* ln2_g = (const float*)d_in[5];
    const float* ln2_b = (const float*)d_in[6];
    const float* xp_mu = (const float*)d_in[7];
    const float* xp_w1 = (const float*)d_in[8];   // (160,512)
    const float* xp_w2 = (const float*)d_in[9];   // (512,160)
    const float* x_bias= (const float*)d_in[10];  // (5,512)
    const float* r_w   = (const float*)d_in[11];  // (256,512)
    const float* w_A   = (const float*)d_in[12];  // (64,512)
    const float* w_B   = (const float*)d_in[13];  // (256,64)
    const float* w_b   = (const float*)d_in[14];  // (256)
    const float* k_w   = (const float*)d_in[15];  // (256,512)
    const float* v_w   = (const float*)d_in[16];  // (512,512)
    const float* g_w   = (const float*)d_in[17];  // (512,512)
    const float* bonus = (const float*)d_in[18];  // (4,64)
    const float* gn_g  = (const float*)d_in[19];  // (128)
    const float* gn_b  = (const float*)d_in[20];
    const float* o_w   = (const float*)d_in[21];  // (512,512)
    const float* fk_mu = (const float*)d_in[22];
    const float* fk_w  = (const float*)d_in[23];  // (1024,512)
    const float* fr_mu = (const float*)d_in[24];
    const float* fr_w  = (const float*)d_in[25];  // (512,512)
    const float* fv_w  = (const float*)d_in[26];  // (512,1024)
    float* out = (float*)d_out;
    (void)in_sizes; (void)n_in; (void)out_size; (void)ws_size;

    const size_t MD = (size_t)Mq * Dq;  // 4M elems
    float* ws = (float*)d_ws;
    size_t off = 0;
    auto af32 = [&](size_t n) { float* p = ws + off; off += n; return p; };

    float* R    = af32(MD);                 // ln0 out (residual), live to o-GEMM
    float* Hb   = af32(MD);                 // ln1 out, live to mix5
    float* XX   = af32((size_t)Mq * 160);   // lora-down (fp32, mix5 A operand)
    float* Rproj= af32((size_t)Mq * 256);
    float* DEC  = af32((size_t)Mq * 256);
    float* KB   = af32((size_t)Mq * 256);
    float* VB   = af32(MD);
    float* GB   = af32(MD);
    float* PC   = af32((size_t)BH2 * NC2 * DKq);         // 64K
    float* S0MC = af32((size_t)BH2 * NC2 * DKq * DVq);   // 8.39M (M_c then S0, in place)
    float* DIAG = af32((size_t)BH2 * Tq);                // 32K

    u16* us = (u16*)(ws + off);
    size_t uo = 0;
    auto au16 = [&](size_t n) { u16* p = us + uo; uo += n; return p; };
    u16* MX0b = au16(MD);          // mix(h,xp_mu) bf16
    u16* AMXb = au16(5 * MD);      // 5 mixed GEMM inputs bf16
    u16* TAb  = au16((size_t)Mq * 64);
    u16* OBb  = au16(MD);          // gatenorm out bf16
    u16* wb_xp1 = au16(256 * 512); // padded 160->256 rows
    u16* wb_r   = au16(256 * 512);
    u16* wb_wA  = au16(128 * 512); // padded 64->128 rows
    u16* wb_wB  = au16(256 * 64);
    u16* wb_k   = au16(256 * 512);
    u16* wb_v   = au16(512 * 512);
    u16* wb_g   = au16(512 * 512);
    u16* wb_o   = au16(512 * 512);
    u16* wb_fk  = au16(1024 * 512);
    u16* wb_fr  = au16(512 * 512);
    u16* wb_fv  = au16(512 * 1024);

    // lifetime-checked aliases (stream-ordered, all disjoint in time):
    float* RQd = (float*)MX0b;            // MX0b dead after xp1-GEMM
    float* KQg = (float*)(AMXb + 4 * MD); // slice 4 dead after proj batch
    float* Z   = GB;                       // a+residual (GB dead after scan_o)
    float* RRb = VB;                       // sigmoid gate (VB dead after scan_o)
    u16* MXKb = AMXb;                      // slice 0 (dead after proj batch)
    u16* MXRb = AMXb + MD;                 // slice 1 (dead after proj batch)
    u16* KKb  = AMXb + 2 * MD;             // slices 2+3 (dead after proj batch)

    // 0) weights -> bf16
    WConv wc;
    const float* wsrc[11] = {xp_w1, r_w, w_A, w_B, k_w, v_w, g_w, o_w, fk_w, fr_w, fv_w};
    u16* wdst[11] = {wb_xp1, wb_r, wb_wA, wb_wB, wb_k, wb_v, wb_g, wb_o, wb_fk, wb_fr, wb_fv};
    int wn_[11]  = {160*512, 256*512, 64*512, 256*64, 256*512, 512*512, 512*512,
                    512*512, 1024*512, 512*512, 512*1024};
    int wnp[11]  = {256*512, 256*512, 128*512, 256*64, 256*512, 512*512, 512*512,
                    512*512, 1024*512, 512*512, 512*1024};
    for (int i = 0; i < 11; i++) { wc.src[i] = wsrc[i]; wc.dst[i] = wdst[i];
                                   wc.n[i] = wn_[i]; wc.npad[i] = wnp[i]; }
    k_wconv<<<dim3(64, 11), 256, 0, stream>>>(wc);

    // 1) pre-norms
    k_ln01<<<Mq, 256, 0, stream>>>(x, ln0_g, ln0_b, ln1_g, ln1_b, R, Hb);

    // 2) xx = tanh(mix(h, xp_mu) @ xp_w1^T)   [MFMA]
    k_mix1<<<Mq, 256, 0, stream>>>(Hb, xp_mu, MX0b);
    k_mgemm<ME_TANH_F32><<<dim3(64, 2), 256, 0, stream>>>(
        MX0b, 512, wb_xp1, 512, XX, 160, 160, 512, nullptr, nullptr, nullptr);

    // 3) mods + the 5 mixed GEMM inputs (K=32, vector fp32, bf16 out)
    k_gemm_mix5<<<dim3(128, 8, 5), 256, 0, stream>>>(XX, xp_w2, x_bias, Hb, AMXb);

    // 4) projections: ONE batched launch {r, wA, k, v, g}  [MFMA, 13 N-tiles]
    {
        MultiDesc md;
        md.g[0] = {AMXb + 0 * MD, wb_r,  (void*)Rproj, 512, 512, 256, 256, 512, 0};
        md.g[1] = {AMXb + 1 * MD, wb_wA, (void*)TAb,   512, 512,  64,  64, 512, 1};
        md.g[2] = {AMXb + 2 * MD, wb_k,  (void*)KB,    512, 512, 256, 256, 512, 0};
        md.g[3] = {AMXb + 3 * MD, wb_v,  (void*)VB,    512, 512, 512, 512, 512, 0};
        md.g[4] = {AMXb + 4 * MD, wb_g,  (void*)GB,    512, 512, 512, 512, 512, 0};
        int gid[16]   = {0,0, 1, 2,2, 3,3,3,3, 4,4,4,4, 0,0,0};
        int ntile[16] = {0,1, 0, 0,1, 0,1,2,3, 0,1,2,3, 0,0,0};
        for (int i = 0; i < 16; i++) { md.gid[i] = gid[i]; md.ntile[i] = ntile[i]; }
        k_mgemm_multi<<<dim3(64, 13), 256, 0, stream>>>(md);
    }
    // wB depends on TAb
    k_mgemm<ME_DECAY><<<dim3(64, 2), 256, 0, stream>>>(
        TAb, 64, wb_wB, 64, DEC, 256, 256, 64, w_b, nullptr, nullptr);

    // 5) chunked matmul scan (+ fused gatenorm/gate in scan_o)
    k_prep_m<<<dim3(NC2, BH2), 256, 0, stream>>>(Rproj, KB, DEC, VB, bonus,
                                                 RQd, KQg, DIAG, PC, S0MC);
    k_combine2<<<(BH2 * DKq * DVq) / 256, 256, 0, stream>>>(S0MC, PC);
    k_scan_o<<<dim3(NC2, BH2), 256, 0, stream>>>(RQd, KQg, VB, S0MC, DIAG,
                                                 GB, gn_g, gn_b, OBb);

    // 6) output proj + residual [MFMA]
    k_mgemm<ME_RESID><<<dim3(64, 4), 256, 0, stream>>>(
        OBb, 512, wb_o, 512, Z, 512, 512, 512, nullptr, R, nullptr);

    // 7) channel-mix FFN: fused ln2+mix, then batched {fk, fr}, then fv [MFMA]
    k_ln2mix<<<Mq, 256, 0, stream>>>(Z, ln2_g, ln2_b, fk_mu, fr_mu, MXKb, MXRb);
    {
        MultiDesc md;
        md.g[0] = {MXKb, wb_fk, (void*)KKb, 512, 512, 1024, 1024, 512, 2};
        md.g[1] = {MXRb, wb_fr, (void*)RRb, 512, 512,  512,  512, 512, 3};
        int gid[16]   = {0,0,0,0,0,0,0,0, 1,1,1,1, 0,0,0,0};
        int ntile[16] = {0,1,2,3,4,5,6,7, 0,1,2,3, 0,0,0,0};
        for (int i = 0; i < 16; i++) { md.gid[i] = gid[i]; md.ntile[i] = ntile[i]; }
        k_mgemm_multi<<<dim3(64, 12), 256, 0, stream>>>(md);
    }
    k_mgemm<ME_GATED><<<dim3(64, 4), 256, 0, stream>>>(
        KKb, 1024, wb_fv, 1024, out, 512, 512, 1024, nullptr, Z, RRb);
}